// Round 4
// baseline (1152.300 us; speedup 1.0000x reference)
//
#include <hip/hip_runtime.h>
#include <hip/hip_bf16.h>

using bf16 = __hip_bfloat16;
typedef __bf16 bf16v8 __attribute__((ext_vector_type(8)));
typedef float f32x4 __attribute__((ext_vector_type(4)));

#define HW 4096      // 64*64 spatial per image
#define ROWS 65536   // 16*HW

__device__ __forceinline__ f32x4 mfma16(const bf16* a, const bf16* b, f32x4 c) {
    bf16v8 av = *(const bf16v8*)a;
    bf16v8 bv = *(const bf16v8*)b;
    return __builtin_amdgcn_mfma_f32_16x16x32_bf16(av, bv, c, 0, 0, 0);
}

// ---------------- zero helper ------------------------------------------------
__global__ void r4_zero(float* __restrict__ p) {
    p[blockIdx.x * 256 + threadIdx.x] = 0.f;
}

// ------- convert+transpose x: fp32 [b][c=128][n] -> bf16 [b][n][c=128] -------
__global__ void r4_cvt_x(const float* __restrict__ x, bf16* __restrict__ xT) {
    __shared__ bf16 tile[64 * 65];
    int b = blockIdx.z, c0 = blockIdx.y * 64, n0 = blockIdx.x * 64;
    int t = threadIdx.x;
    for (int i = 0; i < 16; i++) {
        int idx = i * 256 + t;
        int cc = idx >> 6, nn = idx & 63;
        tile[nn * 65 + cc] = __float2bfloat16(x[((size_t)(b * 128 + c0 + cc)) * HW + n0 + nn]);
    }
    __syncthreads();
    for (int i = 0; i < 16; i++) {
        int idx = i * 256 + t;
        int nn = idx >> 6, cc = idx & 63;
        xT[((size_t)(b * HW + n0 + nn)) * 128 + c0 + cc] = tile[nn * 65 + cc];
    }
}

// ------- convert the 6 plain weight matrices fp32 -> bf16 (one launch) -------
// layout in wbase (bf16 elems): Wsc@0(32768) W1@32768(32768) Wb0@65536(4096)
// Wqkv2@69632(12288) Wqkv3@81920(12288) W2@94208(65536)  total 159744
__global__ void r4_cvt_w(const float* __restrict__ Wsc, const float* __restrict__ W1,
                         const float* __restrict__ Wb0,
                         const float* __restrict__ Wqkv2, const float* __restrict__ Wqkv3,
                         const float* __restrict__ W2, bf16* __restrict__ wbase) {
    int i = blockIdx.x * 256 + threadIdx.x;   // 624 blocks * 256 = 159744 exact
    const float* s; int off;
    if      (i < 32768)  { s = Wsc;   off = i; }
    else if (i < 65536)  { s = W1;    off = i - 32768; }
    else if (i < 69632)  { s = Wb0;   off = i - 65536; }
    else if (i < 81920)  { s = Wqkv2; off = i - 69632; }
    else if (i < 94208)  { s = Wqkv3; off = i - 81920; }
    else                 { s = W2;    off = i - 94208; }
    wbase[i] = __float2bfloat16(s[off]);
}

// ------- pack+convert Wb1 fp32 [o][c][3][3] -> bf16 [tap][o][c] --------------
__global__ void r4_pack3(const float* __restrict__ w, bf16* __restrict__ wp) {
    int i = blockIdx.x * 256 + threadIdx.x;   // 144*256 = 36864 exact
    int tap = i / 4096, rem = i % 4096;
    int o = rem >> 6, c = rem & 63;
    wp[i] = __float2bfloat16(w[(size_t)(o * 64 + c) * 9 + tap]);
}

// ---------------- generic GEMM: out[row][o] = sum_k A[row][k] * W[o][k] ------
__global__ __launch_bounds__(256) void r4_gemm(
        const bf16* __restrict__ A, int a_stride,
        const bf16* __restrict__ Bw, const bf16* __restrict__ Bw2,
        int b_batch_stride, int K,
        bf16* __restrict__ out0, bf16* __restrict__ out1,
        int split, int out_stride) {
    int wave = threadIdx.x >> 6, lane = threadIdx.x & 63;
    int b = blockIdx.z;
    int n_base = blockIdx.x * 64 + wave * 16;
    long grow = (long)b * HW + n_base;
    int lo = lane & 15, quad = lane >> 4;
    const bf16* arow = A + (grow + lo) * (long)a_stride + quad * 8;
    int o_base = blockIdx.y * 64;

    const bf16* wrow[4];
    bf16* obase[4];
    int ocol[4];
#pragma unroll
    for (int ot = 0; ot < 4; ot++) {
        int o = o_base + ot * 16 + lo;
        const bf16* wb;
        if (o < split) { wb = Bw + (long)o * K; obase[ot] = out0; ocol[ot] = o; }
        else           { wb = Bw2 + (long)(o - split) * K; obase[ot] = out1; ocol[ot] = o - split; }
        wrow[ot] = wb + (long)b * b_batch_stride + quad * 8;
    }

    f32x4 acc[4];
#pragma unroll
    for (int ot = 0; ot < 4; ot++) acc[ot] = (f32x4){0.f, 0.f, 0.f, 0.f};

    for (int ks = 0; ks < K; ks += 32) {
#pragma unroll
        for (int ot = 0; ot < 4; ot++)
            acc[ot] = mfma16(arow + ks, wrow[ot] + ks, acc[ot]);
    }
#pragma unroll
    for (int ot = 0; ot < 4; ot++) {
#pragma unroll
        for (int r = 0; r < 4; r++) {
            long row = grow + quad * 4 + r;
            obase[ot][row * out_stride + ocol[ot]] = __float2bfloat16(acc[ot][r]);
        }
    }
}

// ---------------- 3x3 conv on h channels 64..127 (NHWC slice) ----------------
__global__ __launch_bounds__(256) void r4_conv3(
        const bf16* __restrict__ hT, const bf16* __restrict__ wp,
        bf16* __restrict__ obuf) {
    int wave = threadIdx.x >> 6, lane = threadIdx.x & 63;
    int b = blockIdx.y;
    int n_base = blockIdx.x * 64 + wave * 16;
    int y = n_base >> 6, x0 = n_base & 63;
    int lo = lane & 15, quad = lane >> 4;
    int x = x0 + lo;

    f32x4 acc[4];
#pragma unroll
    for (int ot = 0; ot < 4; ot++) acc[ot] = (f32x4){0.f, 0.f, 0.f, 0.f};

    for (int dy = -1; dy <= 1; dy++) {
        int yy = y + dy;
        bool rv = (yy >= 0) && (yy < 64);
        for (int dx = -1; dx <= 1; dx++) {
            int xx = x + dx;
            bool valid = rv && (xx >= 0) && (xx < 64);
            int tap = (dy + 1) * 3 + (dx + 1);
            const bf16* wt = wp + tap * 4096 + quad * 8;
            long srow = (long)b * HW + yy * 64 + xx;
#pragma unroll
            for (int ks = 0; ks < 64; ks += 32) {
                bf16 zbuf[8] = {};
                const bf16* ap = valid ? (hT + srow * 256 + 64 + ks + quad * 8) : zbuf;
                bf16v8 av = valid ? *(const bf16v8*)ap : (bf16v8){0,0,0,0,0,0,0,0};
#pragma unroll
                for (int ot = 0; ot < 4; ot++) {
                    bf16v8 bv = *(const bf16v8*)(wt + (ot * 16 + lo) * 64 + ks);
                    acc[ot] = __builtin_amdgcn_mfma_f32_16x16x32_bf16(av, bv, acc[ot], 0, 0, 0);
                }
            }
        }
    }
    long grow = (long)b * HW + n_base;
#pragma unroll
    for (int ot = 0; ot < 4; ot++) {
        int oc = 64 + ot * 16 + lo;
#pragma unroll
        for (int r = 0; r < 4; r++) {
            long row = grow + quad * 4 + r;
            obuf[row * 256 + oc] = __float2bfloat16(acc[ot][r]);
        }
    }
}

// ---------------- per-channel sum / sumsq over 65536 rows (256 ch) -----------
__global__ void r4_stats(const bf16* __restrict__ src, float* __restrict__ sums) {
    int t = threadIdx.x;
    long r0 = (long)blockIdx.x * 256;
    float s = 0.f, q = 0.f;
    for (int r = 0; r < 256; r++) {
        float v = __bfloat162float(src[(r0 + r) * 256 + t]);
        s += v; q += v * v;
    }
    atomicAdd(&sums[t], s);
    atomicAdd(&sums[256 + t], q);
}

// ---------------- BN + ReLU in place (256 ch), fp32 params -------------------
__global__ void r4_bnrelu(bf16* __restrict__ t_, const float* __restrict__ sums,
                          const float* __restrict__ g0, const float* __restrict__ b0,
                          const float* __restrict__ g1, const float* __restrict__ b1,
                          const float* __restrict__ g2, const float* __restrict__ b2,
                          const float* __restrict__ g3, const float* __restrict__ b3,
                          int quarter) {
    int ch = threadIdx.x;
    const float *gp, *bp; int ci;
    if (quarter) {
        int qi = ch >> 6; ci = ch & 63;
        gp = qi == 0 ? g0 : qi == 1 ? g1 : qi == 2 ? g2 : g3;
        bp = qi == 0 ? b0 : qi == 1 ? b1 : qi == 2 ? b2 : b3;
    } else { gp = g0; bp = b0; ci = ch; }
    float mean = sums[ch] * (1.f / 65536.f);
    float var  = sums[256 + ch] * (1.f / 65536.f) - mean * mean;
    float sc = gp[ci] * rsqrtf(var + 1e-5f);
    float sh = bp[ci] - mean * sc;
    long r0 = (long)blockIdx.x * 256;
    for (int r = 0; r < 256; r++) {
        long idx = (r0 + r) * 256 + ch;
        float v = __bfloat162float(t_[idx]);
        t_[idx] = __float2bfloat16(fmaxf(v * sc + sh, 0.f));
    }
}

// ---------------- softmax stats over spatial for k-slice (256 thr) -----------
__global__ void r4_softstat(const bf16* __restrict__ qkvT,
                            float* __restrict__ mo, float* __restrict__ lo_) {
    __shared__ float red[256];
    __shared__ float mC[64];
    int b = blockIdx.x, t = threadIdx.x, c = t & 63, chunk = t >> 6; // 4 chunks
    const bf16* base = qkvT + (long)b * HW * 192 + 64 + c;
    int n0 = chunk * 1024;
    float mx = -1e30f;
    for (int n = n0; n < n0 + 1024; n++)
        mx = fmaxf(mx, __bfloat162float(base[(long)n * 192]));
    red[t] = mx; __syncthreads();
    if (t < 64) { float m = red[t]; for (int j = 1; j < 4; j++) m = fmaxf(m, red[t + 64 * j]); mC[t] = m; }
    __syncthreads();
    float m = mC[c], s = 0.f;
    for (int n = n0; n < n0 + 1024; n++)
        s += expf(__bfloat162float(base[(long)n * 192]) - m);
    red[t] = s; __syncthreads();
    if (t < 64) {
        float l = red[t]; for (int j = 1; j < 4; j++) l += red[t + 64 * j];
        mo[b * 64 + t] = mC[t]; lo_[b * 64 + t] = l;
    }
}

// ------- apply softmax to k, transpose k,v to [b][c][n] ----------------------
__global__ void r4_softapply(const bf16* __restrict__ qkvT,
                             const float* __restrict__ m_in, const float* __restrict__ l_in,
                             bf16* __restrict__ softk, bf16* __restrict__ vcn) {
    __shared__ bf16 lk[64 * 65];
    __shared__ bf16 lv[64 * 65];
    __shared__ float mS[64], ilS[64];
    int b = blockIdx.y, n0 = blockIdx.x * 64;
    int t = threadIdx.x;
    if (t < 64) { mS[t] = m_in[b * 64 + t]; ilS[t] = 1.f / l_in[b * 64 + t]; }
    __syncthreads();
    for (int i = 0; i < 16; i++) {
        int idx = i * 256 + t; int r = idx >> 6, c = idx & 63;
        const bf16* row = qkvT + ((long)b * HW + n0 + r) * 192;
        float kv = __bfloat162float(row[64 + c]);
        lk[c * 65 + r] = __float2bfloat16(expf(kv - mS[c]) * ilS[c]);
        lv[c * 65 + r] = row[128 + c];
    }
    __syncthreads();
    for (int i = 0; i < 16; i++) {
        int idx = i * 256 + t; int c = idx >> 6, r = idx & 63;
        long o = ((long)b * 64 + c) * HW + n0 + r;
        softk[o] = lk[c * 65 + r];
        vcn[o]   = lv[c * 65 + r];
    }
}

// ---------------- ctx[b][c][d] = sum_n softk[c][n] * v[d][n] -----------------
__global__ __launch_bounds__(256) void r4_ctx(
        const bf16* __restrict__ softk, const bf16* __restrict__ vcn,
        float* __restrict__ ctx) {
    int wave = threadIdx.x >> 6, lane = threadIdx.x & 63;
    int b = blockIdx.y;
    int n0 = blockIdx.x * 512;
    int lo = lane & 15, quad = lane >> 4;
    const bf16* arow  = softk + ((long)b * 64 + wave * 16 + lo) * HW + n0 + quad * 8;
    const bf16* bbase = vcn + (long)b * 64 * HW + n0 + quad * 8;
    f32x4 acc[4];
#pragma unroll
    for (int ot = 0; ot < 4; ot++) acc[ot] = (f32x4){0.f, 0.f, 0.f, 0.f};
    for (int ks = 0; ks < 512; ks += 32) {
#pragma unroll
        for (int ot = 0; ot < 4; ot++)
            acc[ot] = mfma16(arow + ks, bbase + (ot * 16 + lo) * HW + ks, acc[ot]);
    }
#pragma unroll
    for (int ot = 0; ot < 4; ot++) {
#pragma unroll
        for (int r = 0; r < 4; r++) {
            int c = wave * 16 + quad * 4 + r;
            int d = ot * 16 + lo;
            atomicAdd(&ctx[((long)b * 64 + c) * 64 + d], acc[ot][r]);
        }
    }
}

// ------- M[b][e][c] = sum_d Wproj[e][d] * ctx[b][c][d]  (Wproj fp32) ---------
__global__ void r4_mproj(const float* __restrict__ Wp, const float* __restrict__ ctx,
                         bf16* __restrict__ M) {
    __shared__ float lw[4096];
    __shared__ float lc[64];
    int b = blockIdx.x, e = threadIdx.x;
    for (int i = e; i < 4096; i += 64) lw[i] = Wp[i];
    __syncthreads();
    const float* cb = ctx + (long)b * 4096;
    for (int c = 0; c < 64; c++) {
        lc[e] = cb[c * 64 + e];
        __syncthreads();
        float a = 0.f;
        for (int d = 0; d < 64; d++) a += lw[e * 64 + d] * lc[d];
        M[(long)b * 4096 + e * 64 + c] = __float2bfloat16(a);
        __syncthreads();
    }
}

// --------- final: relu(bn2(y2) + bnsc(ysc)), write fp32 NCHW -----------------
__global__ void r4_final(const bf16* __restrict__ y2, const bf16* __restrict__ ysc,
                         const float* __restrict__ s2sums, const float* __restrict__ scsums,
                         const float* __restrict__ g2, const float* __restrict__ b2,
                         const float* __restrict__ gsc, const float* __restrict__ bsc,
                         float* __restrict__ out) {
    __shared__ float lo_[64 * 65];
    __shared__ float sc2[64], sh2[64], scc[64], shc[64];
    int b = blockIdx.z, c0 = blockIdx.y * 64, n0 = blockIdx.x * 64;
    int t = threadIdx.x;
    if (t < 64) {
        int ch = c0 + t;
        float m2 = s2sums[ch] * (1.f / 65536.f);
        float v2 = s2sums[256 + ch] * (1.f / 65536.f) - m2 * m2;
        float s = g2[ch] * rsqrtf(v2 + 1e-5f);
        sc2[t] = s; sh2[t] = b2[ch] - m2 * s;
        float mc = scsums[ch] * (1.f / 65536.f);
        float vc = scsums[256 + ch] * (1.f / 65536.f) - mc * mc;
        float s2_ = gsc[ch] * rsqrtf(vc + 1e-5f);
        scc[t] = s2_; shc[t] = bsc[ch] - mc * s2_;
    }
    __syncthreads();
    for (int i = 0; i < 16; i++) {
        int idx = i * 256 + t; int r = idx >> 6, c = idx & 63;
        long row = (long)b * HW + n0 + r;
        float v = __bfloat162float(y2[row * 256 + c0 + c]) * sc2[c] + sh2[c]
                + __bfloat162float(ysc[row * 256 + c0 + c]) * scc[c] + shc[c];
        lo_[c * 65 + r] = fmaxf(v, 0.f);
    }
    __syncthreads();
    for (int i = 0; i < 16; i++) {
        int idx = i * 256 + t; int c = idx >> 6, r = idx & 63;
        out[((long)b * 256 + c0 + c) * HW + n0 + r] = lo_[c * 65 + r];
    }
}

extern "C" void kernel_launch(void* const* d_in, const int* in_sizes, int n_in,
                              void* d_out, int out_size, void* d_ws, size_t ws_size,
                              hipStream_t stream) {
    // ---- inputs are FLOAT32 per the reference (setup_inputs: jnp.float32) ----
    const float* x     = (const float*)d_in[0];
    const float* Wsc   = (const float*)d_in[1];
    const float* gsc   = (const float*)d_in[2];
    const float* bsc   = (const float*)d_in[3];
    const float* W1    = (const float*)d_in[4];
    const float* g1    = (const float*)d_in[5];
    const float* b1    = (const float*)d_in[6];
    const float* Wb0   = (const float*)d_in[7];
    const float* gb0   = (const float*)d_in[8];
    const float* bb0   = (const float*)d_in[9];
    const float* Wb1   = (const float*)d_in[10];
    const float* gb1   = (const float*)d_in[11];
    const float* bb1   = (const float*)d_in[12];
    const float* Wqkv2 = (const float*)d_in[13];
    const float* Wproj2= (const float*)d_in[14];
    const float* ga2   = (const float*)d_in[15];
    const float* ba2   = (const float*)d_in[16];
    const float* Wqkv3 = (const float*)d_in[17];
    const float* Wproj3= (const float*)d_in[18];
    const float* ga3   = (const float*)d_in[19];
    const float* ba3   = (const float*)d_in[20];
    const float* W2    = (const float*)d_in[21];
    const float* g2    = (const float*)d_in[22];
    const float* b2    = (const float*)d_in[23];

    // ---- workspace map (total 84934656 B = 81 MiB) ----
    char* ws = (char*)d_ws;
    float* stats = (float*)ws;                 // 4096 floats: [0)ysc [512)y1 [1024)obuf [1536)y2 [2048)m [3072)l
    float* ctx   = (float*)(ws + 16384);       // [16][64][64] fp32 = 262144 B -> 278528
    bf16*  M     = (bf16*)(ws + 278528);       // [16][64][64] bf16 = 131072 B -> 409600
    bf16*  wbase = (bf16*)(ws + 409600);       // 159744 bf16 = 319488 B -> 729088
    bf16*  wsc_b = wbase;                      // 256x128
    bf16*  w1_b  = wbase + 32768;              // 256x128
    bf16*  wb0_b = wbase + 65536;              // 64x64
    bf16*  wq2_b = wbase + 69632;              // 192x64
    bf16*  wq3_b = wbase + 81920;              // 192x64
    bf16*  w2_b  = wbase + 94208;              // 256x256
    bf16*  wb1p  = (bf16*)(ws + 729088);       // packed 3x3: 36864 bf16 = 73728 B -> 802816
    bf16*  xT    = (bf16*)(ws + 1048576);      // [65536][128] bf16 = 16 MiB; dead after 1st GEMM
    bf16*  sk    = xT;                         // [16][64][4096] = 8 MiB (reuses xT)
    bf16*  vcn   = (bf16*)(ws + 1048576 + 8388608); // 8 MiB (reuses xT)
    bf16*  ysc   = (bf16*)(ws + 17825792);     // [65536][256] bf16 = 32 MiB (residual, live to end)
    bf16*  y1    = (bf16*)(ws + 51380224);     // [65536][256] bf16 = 32 MiB
    bf16*  y2    = y1;                         // alias: y1 dead after branch-3 qkv GEMM
    // d_out (64 MiB fp32) doubles as bf16 scratch until r4_final:
    bf16*  obuf  = (bf16*)d_out;               // [65536][256] bf16 = 32 MiB @ offset 0
    bf16*  qkv   = (bf16*)((char*)d_out + 33554432); // [65536][192] bf16 = 24 MiB

    r4_zero<<<dim3(16), 256, 0, stream>>>(stats);
    r4_cvt_w<<<dim3(624), 256, 0, stream>>>(Wsc, W1, Wb0, Wqkv2, Wqkv3, W2, wbase);
    r4_pack3<<<dim3(144), 256, 0, stream>>>(Wb1, wb1p);
    r4_cvt_x<<<dim3(64, 2, 16), 256, 0, stream>>>(x, xT);

    // conv_sc + conv1 fused as one 512-wide GEMM
    r4_gemm<<<dim3(64, 8, 16), 256, 0, stream>>>(xT, 128, wsc_b, w1_b, 0, 128,
                                                 ysc, y1, 256, 256);
    r4_stats<<<dim3(256), 256, 0, stream>>>(ysc, stats + 0);
    r4_stats<<<dim3(256), 256, 0, stream>>>(y1, stats + 512);
    r4_bnrelu<<<dim3(256), 256, 0, stream>>>(y1, stats + 512, g1, b1, g1, b1, g1, b1, g1, b1, 0);

    // branch 0 (1x1) and branch 1 (3x3) into obuf cols [0:64) and [64:128)
    r4_gemm<<<dim3(64, 1, 16), 256, 0, stream>>>(y1, 256, wb0_b, wb0_b, 0, 64,
                                                 obuf, obuf, 1 << 28, 256);
    r4_conv3<<<dim3(64, 16), 256, 0, stream>>>(y1, wb1p, obuf);

    // branch 2 (LGA on s2 = y1 cols 128..191) -> obuf cols [128:192)
    r4_gemm<<<dim3(64, 3, 16), 256, 0, stream>>>(y1 + 128, 256, wq2_b, wq2_b, 0, 64,
                                                 qkv, qkv, 1 << 28, 192);
    r4_softstat<<<dim3(16), 256, 0, stream>>>(qkv, stats + 2048, stats + 3072);
    r4_softapply<<<dim3(64, 16), 256, 0, stream>>>(qkv, stats + 2048, stats + 3072, sk, vcn);
    r4_zero<<<dim3(256), 256, 0, stream>>>(ctx);
    r4_ctx<<<dim3(8, 16), 256, 0, stream>>>(sk, vcn, ctx);
    r4_mproj<<<dim3(16), 64, 0, stream>>>(Wproj2, ctx, M);
    r4_gemm<<<dim3(64, 1, 16), 256, 0, stream>>>(qkv, 192, M, M, 4096, 64,
                                                 obuf + 128, obuf + 128, 1 << 28, 256);

    // branch 3 (LGA on s3 = y1 cols 192..255) -> obuf cols [192:256)
    r4_gemm<<<dim3(64, 3, 16), 256, 0, stream>>>(y1 + 192, 256, wq3_b, wq3_b, 0, 64,
                                                 qkv, qkv, 1 << 28, 192);
    r4_softstat<<<dim3(16), 256, 0, stream>>>(qkv, stats + 2048, stats + 3072);
    r4_softapply<<<dim3(64, 16), 256, 0, stream>>>(qkv, stats + 2048, stats + 3072, sk, vcn);
    r4_zero<<<dim3(256), 256, 0, stream>>>(ctx);
    r4_ctx<<<dim3(8, 16), 256, 0, stream>>>(sk, vcn, ctx);
    r4_mproj<<<dim3(16), 64, 0, stream>>>(Wproj3, ctx, M);
    r4_gemm<<<dim3(64, 1, 16), 256, 0, stream>>>(qkv, 192, M, M, 4096, 64,
                                                 obuf + 192, obuf + 192, 1 << 28, 256);

    // concat BN + ReLU (per-quarter params), then conv2
    r4_stats<<<dim3(256), 256, 0, stream>>>(obuf, stats + 1024);
    r4_bnrelu<<<dim3(256), 256, 0, stream>>>(obuf, stats + 1024,
                                             gb0, bb0, gb1, bb1, ga2, ba2, ga3, ba3, 1);
    r4_gemm<<<dim3(64, 4, 16), 256, 0, stream>>>(obuf, 256, w2_b, w2_b, 0, 256,
                                                 y2, y2, 1 << 28, 256);
    r4_stats<<<dim3(256), 256, 0, stream>>>(y2, stats + 1536);
    r4_final<<<dim3(64, 4, 16), 256, 0, stream>>>(y2, ysc, stats + 1536, stats + 0,
                                                  g2, b2, gsc, bsc, (float*)d_out);
}

// Round 5
// 690.307 us; speedup vs baseline: 1.6693x; 1.6693x over previous
//
#include <hip/hip_runtime.h>
#include <hip/hip_bf16.h>

using bf16 = __hip_bfloat16;
typedef __bf16 bf16v8 __attribute__((ext_vector_type(8)));
typedef float f32x4 __attribute__((ext_vector_type(4)));

#define HW 4096      // 64*64 spatial per image
#define ROWS 65536   // 16*HW

__device__ __forceinline__ f32x4 mfma16(const bf16* a, const bf16* b, f32x4 c) {
    bf16v8 av = *(const bf16v8*)a;
    bf16v8 bv = *(const bf16v8*)b;
    return __builtin_amdgcn_mfma_f32_16x16x32_bf16(av, bv, c, 0, 0, 0);
}

// ordered-int mapping for float atomicMax
__device__ __forceinline__ int f2oi(float f) { int i = __float_as_int(f); return i >= 0 ? i : i ^ 0x7FFFFFFF; }
__device__ __forceinline__ float oi2f(int i) { return __int_as_float(i >= 0 ? i : i ^ 0x7FFFFFFF); }

// ---------------- zero helper ------------------------------------------------
__global__ void r4_zero(float* __restrict__ p) {
    p[blockIdx.x * 256 + threadIdx.x] = 0.f;
}

// ------- init: BN sums (2048 f) = 0; softmax m/l slots for both branches -----
__global__ void r5_init(float* __restrict__ stats, int* __restrict__ mo2, float* __restrict__ lo2,
                        int* __restrict__ mo3, float* __restrict__ lo3) {
    int i = blockIdx.x * 256 + threadIdx.x;   // 8 blocks * 256 = 2048
    stats[i] = 0.f;
    if (i < 1024) {
        int neg = f2oi(-1e30f);
        mo2[i] = neg; lo2[i] = 0.f;
        mo3[i] = neg; lo3[i] = 0.f;
    }
}

// ------- convert+transpose x: fp32 [b][c=128][n] -> bf16 [b][n][c=128] -------
__global__ void r4_cvt_x(const float* __restrict__ x, bf16* __restrict__ xT) {
    __shared__ bf16 tile[64 * 65];
    int b = blockIdx.z, c0 = blockIdx.y * 64, n0 = blockIdx.x * 64;
    int t = threadIdx.x;
    for (int i = 0; i < 16; i++) {
        int idx = i * 256 + t;
        int cc = idx >> 6, nn = idx & 63;
        tile[nn * 65 + cc] = __float2bfloat16(x[((size_t)(b * 128 + c0 + cc)) * HW + n0 + nn]);
    }
    __syncthreads();
    for (int i = 0; i < 16; i++) {
        int idx = i * 256 + t;
        int nn = idx >> 6, cc = idx & 63;
        xT[((size_t)(b * HW + n0 + nn)) * 128 + c0 + cc] = tile[nn * 65 + cc];
    }
}

// ------- convert the 6 plain weight matrices fp32 -> bf16 (one launch) -------
__global__ void r4_cvt_w(const float* __restrict__ Wsc, const float* __restrict__ W1,
                         const float* __restrict__ Wb0,
                         const float* __restrict__ Wqkv2, const float* __restrict__ Wqkv3,
                         const float* __restrict__ W2, bf16* __restrict__ wbase) {
    int i = blockIdx.x * 256 + threadIdx.x;   // 624 blocks * 256 = 159744 exact
    const float* s; int off;
    if      (i < 32768)  { s = Wsc;   off = i; }
    else if (i < 65536)  { s = W1;    off = i - 32768; }
    else if (i < 69632)  { s = Wb0;   off = i - 65536; }
    else if (i < 81920)  { s = Wqkv2; off = i - 69632; }
    else if (i < 94208)  { s = Wqkv3; off = i - 81920; }
    else                 { s = W2;    off = i - 94208; }
    wbase[i] = __float2bfloat16(s[off]);
}

// ------- pack+convert Wb1 fp32 [o][c][3][3] -> bf16 [tap][o][c] --------------
__global__ void r4_pack3(const float* __restrict__ w, bf16* __restrict__ wp) {
    int i = blockIdx.x * 256 + threadIdx.x;   // 144*256 = 36864 exact
    int tap = i / 4096, rem = i % 4096;
    int o = rem >> 6, c = rem & 63;
    wp[i] = __float2bfloat16(w[(size_t)(o * 64 + c) * 9 + tap]);
}

// ---------------- generic GEMM: out[row][o] = sum_k A[row][k] * W[o][k] ------
__global__ __launch_bounds__(256) void r4_gemm(
        const bf16* __restrict__ A, int a_stride,
        const bf16* __restrict__ Bw, const bf16* __restrict__ Bw2,
        int b_batch_stride, int K,
        bf16* __restrict__ out0, bf16* __restrict__ out1,
        int split, int out_stride) {
    int wave = threadIdx.x >> 6, lane = threadIdx.x & 63;
    int b = blockIdx.z;
    int n_base = blockIdx.x * 64 + wave * 16;
    long grow = (long)b * HW + n_base;
    int lo = lane & 15, quad = lane >> 4;
    const bf16* arow = A + (grow + lo) * (long)a_stride + quad * 8;
    int o_base = blockIdx.y * 64;

    const bf16* wrow[4];
    bf16* obase[4];
    int ocol[4];
#pragma unroll
    for (int ot = 0; ot < 4; ot++) {
        int o = o_base + ot * 16 + lo;
        const bf16* wb;
        if (o < split) { wb = Bw + (long)o * K; obase[ot] = out0; ocol[ot] = o; }
        else           { wb = Bw2 + (long)(o - split) * K; obase[ot] = out1; ocol[ot] = o - split; }
        wrow[ot] = wb + (long)b * b_batch_stride + quad * 8;
    }

    f32x4 acc[4];
#pragma unroll
    for (int ot = 0; ot < 4; ot++) acc[ot] = (f32x4){0.f, 0.f, 0.f, 0.f};

    for (int ks = 0; ks < K; ks += 32) {
#pragma unroll
        for (int ot = 0; ot < 4; ot++)
            acc[ot] = mfma16(arow + ks, wrow[ot] + ks, acc[ot]);
    }
#pragma unroll
    for (int ot = 0; ot < 4; ot++) {
#pragma unroll
        for (int r = 0; r < 4; r++) {
            long row = grow + quad * 4 + r;
            obase[ot][row * out_stride + ocol[ot]] = __float2bfloat16(acc[ot][r]);
        }
    }
}

// ---------------- 3x3 conv on h channels 64..127 (NHWC slice) ----------------
__global__ __launch_bounds__(256) void r4_conv3(
        const bf16* __restrict__ hT, const bf16* __restrict__ wp,
        bf16* __restrict__ obuf) {
    int wave = threadIdx.x >> 6, lane = threadIdx.x & 63;
    int b = blockIdx.y;
    int n_base = blockIdx.x * 64 + wave * 16;
    int y = n_base >> 6, x0 = n_base & 63;
    int lo = lane & 15, quad = lane >> 4;
    int x = x0 + lo;

    f32x4 acc[4];
#pragma unroll
    for (int ot = 0; ot < 4; ot++) acc[ot] = (f32x4){0.f, 0.f, 0.f, 0.f};

    for (int dy = -1; dy <= 1; dy++) {
        int yy = y + dy;
        bool rv = (yy >= 0) && (yy < 64);
        for (int dx = -1; dx <= 1; dx++) {
            int xx = x + dx;
            bool valid = rv && (xx >= 0) && (xx < 64);
            int tap = (dy + 1) * 3 + (dx + 1);
            const bf16* wt = wp + tap * 4096 + quad * 8;
            long srow = (long)b * HW + yy * 64 + xx;
#pragma unroll
            for (int ks = 0; ks < 64; ks += 32) {
                bf16v8 av = (bf16v8){0,0,0,0,0,0,0,0};
                if (valid) av = *(const bf16v8*)(hT + srow * 256 + 64 + ks + quad * 8);
#pragma unroll
                for (int ot = 0; ot < 4; ot++) {
                    bf16v8 bv = *(const bf16v8*)(wt + (ot * 16 + lo) * 64 + ks);
                    acc[ot] = __builtin_amdgcn_mfma_f32_16x16x32_bf16(av, bv, acc[ot], 0, 0, 0);
                }
            }
        }
    }
    long grow = (long)b * HW + n_base;
#pragma unroll
    for (int ot = 0; ot < 4; ot++) {
        int oc = 64 + ot * 16 + lo;
#pragma unroll
        for (int r = 0; r < 4; r++) {
            long row = grow + quad * 4 + r;
            obuf[row * 256 + oc] = __float2bfloat16(acc[ot][r]);
        }
    }
}

// ---------------- per-channel sum / sumsq over 65536 rows (256 ch) -----------
__global__ void r4_stats(const bf16* __restrict__ src, float* __restrict__ sums) {
    int t = threadIdx.x;
    long r0 = (long)blockIdx.x * 256;
    float s = 0.f, q = 0.f;
    for (int r = 0; r < 256; r++) {
        float v = __bfloat162float(src[(r0 + r) * 256 + t]);
        s += v; q += v * v;
    }
    atomicAdd(&sums[t], s);
    atomicAdd(&sums[256 + t], q);
}

// ---------------- BN + ReLU in place (256 ch), fp32 params -------------------
__global__ void r4_bnrelu(bf16* __restrict__ t_, const float* __restrict__ sums,
                          const float* __restrict__ g0, const float* __restrict__ b0,
                          const float* __restrict__ g1, const float* __restrict__ b1,
                          const float* __restrict__ g2, const float* __restrict__ b2,
                          const float* __restrict__ g3, const float* __restrict__ b3,
                          int quarter) {
    int ch = threadIdx.x;
    const float *gp, *bp; int ci;
    if (quarter) {
        int qi = ch >> 6; ci = ch & 63;
        gp = qi == 0 ? g0 : qi == 1 ? g1 : qi == 2 ? g2 : g3;
        bp = qi == 0 ? b0 : qi == 1 ? b1 : qi == 2 ? b2 : b3;
    } else { gp = g0; bp = b0; ci = ch; }
    float mean = sums[ch] * (1.f / 65536.f);
    float var  = sums[256 + ch] * (1.f / 65536.f) - mean * mean;
    float sc = gp[ci] * rsqrtf(var + 1e-5f);
    float sh = bp[ci] - mean * sc;
    long r0 = (long)blockIdx.x * 256;
    for (int r = 0; r < 256; r++) {
        long idx = (r0 + r) * 256 + ch;
        float v = __bfloat162float(t_[idx]);
        t_[idx] = __float2bfloat16(fmaxf(v * sc + sh, 0.f));
    }
}

// ------- per-(b,c) max of k-slice, wide grid + ordered-int atomicMax ---------
__global__ void r5_kmax(const bf16* __restrict__ qkvT, int* __restrict__ mo) {
    __shared__ float red[256];
    int b = blockIdx.y, t = threadIdx.x, c = t & 63, sub = t >> 6;   // 4 subs
    long n0 = (long)blockIdx.x * 128 + sub * 32;
    const bf16* base = qkvT + ((long)b * HW + n0) * 192 + 64 + c;
    float mx = -1e30f;
    for (int n = 0; n < 32; n++)
        mx = fmaxf(mx, __bfloat162float(base[n * 192]));
    red[t] = mx; __syncthreads();
    if (t < 64) {
        float m = fmaxf(fmaxf(red[t], red[t + 64]), fmaxf(red[t + 128], red[t + 192]));
        atomicMax(&mo[b * 64 + t], f2oi(m));
    }
}

// ------- per-(b,c) sum of exp(k - m), wide grid + atomicAdd ------------------
__global__ void r5_ksum(const bf16* __restrict__ qkvT, const int* __restrict__ mo,
                        float* __restrict__ lo_) {
    __shared__ float red[256];
    int b = blockIdx.y, t = threadIdx.x, c = t & 63, sub = t >> 6;
    long n0 = (long)blockIdx.x * 128 + sub * 32;
    float m = oi2f(mo[b * 64 + c]);
    const bf16* base = qkvT + ((long)b * HW + n0) * 192 + 64 + c;
    float s = 0.f;
    for (int n = 0; n < 32; n++)
        s += expf(__bfloat162float(base[n * 192]) - m);
    red[t] = s; __syncthreads();
    if (t < 64) {
        float tot = red[t] + red[t + 64] + red[t + 128] + red[t + 192];
        atomicAdd(&lo_[b * 64 + t], tot);
    }
}

// ------- apply softmax to k, transpose k,v to [b][c][n] ----------------------
__global__ void r4_softapply(const bf16* __restrict__ qkvT,
                             const int* __restrict__ m_in, const float* __restrict__ l_in,
                             bf16* __restrict__ softk, bf16* __restrict__ vcn) {
    __shared__ bf16 lk[64 * 65];
    __shared__ bf16 lv[64 * 65];
    __shared__ float mS[64], ilS[64];
    int b = blockIdx.y, n0 = blockIdx.x * 64;
    int t = threadIdx.x;
    if (t < 64) { mS[t] = oi2f(m_in[b * 64 + t]); ilS[t] = 1.f / l_in[b * 64 + t]; }
    __syncthreads();
    for (int i = 0; i < 16; i++) {
        int idx = i * 256 + t; int r = idx >> 6, c = idx & 63;
        const bf16* row = qkvT + ((long)b * HW + n0 + r) * 192;
        float kv = __bfloat162float(row[64 + c]);
        lk[c * 65 + r] = __float2bfloat16(expf(kv - mS[c]) * ilS[c]);
        lv[c * 65 + r] = row[128 + c];
    }
    __syncthreads();
    for (int i = 0; i < 16; i++) {
        int idx = i * 256 + t; int c = idx >> 6, r = idx & 63;
        long o = ((long)b * 64 + c) * HW + n0 + r;
        softk[o] = lk[c * 65 + r];
        vcn[o]   = lv[c * 65 + r];
    }
}

// ---------------- ctx[b][c][d] = sum_n softk[c][n] * v[d][n] -----------------
__global__ __launch_bounds__(256) void r4_ctx(
        const bf16* __restrict__ softk, const bf16* __restrict__ vcn,
        float* __restrict__ ctx) {
    int wave = threadIdx.x >> 6, lane = threadIdx.x & 63;
    int b = blockIdx.y;
    int n0 = blockIdx.x * 512;
    int lo = lane & 15, quad = lane >> 4;
    const bf16* arow  = softk + ((long)b * 64 + wave * 16 + lo) * HW + n0 + quad * 8;
    const bf16* bbase = vcn + (long)b * 64 * HW + n0 + quad * 8;
    f32x4 acc[4];
#pragma unroll
    for (int ot = 0; ot < 4; ot++) acc[ot] = (f32x4){0.f, 0.f, 0.f, 0.f};
    for (int ks = 0; ks < 512; ks += 32) {
#pragma unroll
        for (int ot = 0; ot < 4; ot++)
            acc[ot] = mfma16(arow + ks, bbase + (ot * 16 + lo) * HW + ks, acc[ot]);
    }
#pragma unroll
    for (int ot = 0; ot < 4; ot++) {
#pragma unroll
        for (int r = 0; r < 4; r++) {
            int c = wave * 16 + quad * 4 + r;
            int d = ot * 16 + lo;
            atomicAdd(&ctx[((long)b * 64 + c) * 64 + d], acc[ot][r]);
        }
    }
}

// ------- M[b][e][c] = sum_d Wproj[e][d] * ctx[b][c][d]  (Wproj fp32) ---------
__global__ void r4_mproj(const float* __restrict__ Wp, const float* __restrict__ ctx,
                         bf16* __restrict__ M) {
    __shared__ float lw[4096];
    __shared__ float lc[64];
    int b = blockIdx.x, e = threadIdx.x;
    for (int i = e; i < 4096; i += 64) lw[i] = Wp[i];
    __syncthreads();
    const float* cb = ctx + (long)b * 4096;
    for (int c = 0; c < 64; c++) {
        lc[e] = cb[c * 64 + e];
        __syncthreads();
        float a = 0.f;
        for (int d = 0; d < 64; d++) a += lw[e * 64 + d] * lc[d];
        M[(long)b * 4096 + e * 64 + c] = __float2bfloat16(a);
        __syncthreads();
    }
}

// --------- final: relu(bn2(y2) + bnsc(ysc)), write fp32 NCHW -----------------
__global__ void r4_final(const bf16* __restrict__ y2, const bf16* __restrict__ ysc,
                         const float* __restrict__ s2sums, const float* __restrict__ scsums,
                         const float* __restrict__ g2, const float* __restrict__ b2,
                         const float* __restrict__ gsc, const float* __restrict__ bsc,
                         float* __restrict__ out) {
    __shared__ float lo_[64 * 65];
    __shared__ float sc2[64], sh2[64], scc[64], shc[64];
    int b = blockIdx.z, c0 = blockIdx.y * 64, n0 = blockIdx.x * 64;
    int t = threadIdx.x;
    if (t < 64) {
        int ch = c0 + t;
        float m2 = s2sums[ch] * (1.f / 65536.f);
        float v2 = s2sums[256 + ch] * (1.f / 65536.f) - m2 * m2;
        float s = g2[ch] * rsqrtf(v2 + 1e-5f);
        sc2[t] = s; sh2[t] = b2[ch] - m2 * s;
        float mc = scsums[ch] * (1.f / 65536.f);
        float vc = scsums[256 + ch] * (1.f / 65536.f) - mc * mc;
        float s2_ = gsc[ch] * rsqrtf(vc + 1e-5f);
        scc[t] = s2_; shc[t] = bsc[ch] - mc * s2_;
    }
    __syncthreads();
    for (int i = 0; i < 16; i++) {
        int idx = i * 256 + t; int r = idx >> 6, c = idx & 63;
        long row = (long)b * HW + n0 + r;
        float v = __bfloat162float(y2[row * 256 + c0 + c]) * sc2[c] + sh2[c]
                + __bfloat162float(ysc[row * 256 + c0 + c]) * scc[c] + shc[c];
        lo_[c * 65 + r] = fmaxf(v, 0.f);
    }
    __syncthreads();
    for (int i = 0; i < 16; i++) {
        int idx = i * 256 + t; int c = idx >> 6, r = idx & 63;
        out[((long)b * 256 + c0 + c) * HW + n0 + r] = lo_[c * 65 + r];
    }
}

extern "C" void kernel_launch(void* const* d_in, const int* in_sizes, int n_in,
                              void* d_out, int out_size, void* d_ws, size_t ws_size,
                              hipStream_t stream) {
    const float* x     = (const float*)d_in[0];
    const float* Wsc   = (const float*)d_in[1];
    const float* gsc   = (const float*)d_in[2];
    const float* bsc   = (const float*)d_in[3];
    const float* W1    = (const float*)d_in[4];
    const float* g1    = (const float*)d_in[5];
    const float* b1    = (const float*)d_in[6];
    const float* Wb0   = (const float*)d_in[7];
    const float* gb0   = (const float*)d_in[8];
    const float* bb0   = (const float*)d_in[9];
    const float* Wb1   = (const float*)d_in[10];
    const float* gb1   = (const float*)d_in[11];
    const float* bb1   = (const float*)d_in[12];
    const float* Wqkv2 = (const float*)d_in[13];
    const float* Wproj2= (const float*)d_in[14];
    const float* ga2   = (const float*)d_in[15];
    const float* ba2   = (const float*)d_in[16];
    const float* Wqkv3 = (const float*)d_in[17];
    const float* Wproj3= (const float*)d_in[18];
    const float* ga3   = (const float*)d_in[19];
    const float* ba3   = (const float*)d_in[20];
    const float* W2    = (const float*)d_in[21];
    const float* g2    = (const float*)d_in[22];
    const float* b2    = (const float*)d_in[23];

    // ---- workspace map ----
    char* ws = (char*)d_ws;
    float* stats = (float*)ws;                 // 2048 floats BN sums: [0)ysc [512)y1 [1024)obuf [1536)y2
    int*   mo2   = (int*)(ws + 8192);          // 1024 ints
    float* lo2   = (float*)(ws + 12288);       // 1024 floats
    int*   mo3   = (int*)(ws + 16384);
    float* lo3   = (float*)(ws + 20480);
    float* ctx   = (float*)(ws + 24576);       // [16][64][64] fp32 = 262144 B -> 286720
    bf16*  M     = (bf16*)(ws + 286720);       // [16][64][64] bf16 = 131072 B -> 417792
    bf16*  wbase = (bf16*)(ws + 417792);       // 159744 bf16 = 319488 B -> 737280
    bf16*  wsc_b = wbase;                      // 256x128
    bf16*  w1_b  = wbase + 32768;              // 256x128
    bf16*  wb0_b = wbase + 65536;              // 64x64
    bf16*  wq2_b = wbase + 69632;              // 192x64
    bf16*  wq3_b = wbase + 81920;              // 192x64
    bf16*  w2_b  = wbase + 94208;              // 256x256
    bf16*  wb1p  = (bf16*)(ws + 737280);       // packed 3x3: 73728 B -> 811008
    bf16*  xT    = (bf16*)(ws + 1048576);      // [65536][128] bf16 = 16 MiB; dead after 1st GEMM
    bf16*  sk    = xT;                         // [16][64][4096] = 8 MiB (reuses xT)
    bf16*  vcn   = (bf16*)(ws + 1048576 + 8388608); // 8 MiB (reuses xT)
    bf16*  ysc   = (bf16*)(ws + 17825792);     // [65536][256] bf16 = 32 MiB (residual, live to end)
    bf16*  y1    = (bf16*)(ws + 51380224);     // [65536][256] bf16 = 32 MiB
    bf16*  y2    = y1;                         // alias: y1 dead after branch-3 qkv GEMM
    bf16*  obuf  = (bf16*)d_out;               // [65536][256] bf16 = 32 MiB @ offset 0 of d_out
    bf16*  qkv   = (bf16*)((char*)d_out + 33554432); // [65536][192] bf16 = 24 MiB

    r5_init<<<dim3(8), 256, 0, stream>>>(stats, mo2, lo2, mo3, lo3);
    r4_cvt_w<<<dim3(624), 256, 0, stream>>>(Wsc, W1, Wb0, Wqkv2, Wqkv3, W2, wbase);
    r4_pack3<<<dim3(144), 256, 0, stream>>>(Wb1, wb1p);
    r4_cvt_x<<<dim3(64, 2, 16), 256, 0, stream>>>(x, xT);

    // conv_sc + conv1 fused as one 512-wide GEMM
    r4_gemm<<<dim3(64, 8, 16), 256, 0, stream>>>(xT, 128, wsc_b, w1_b, 0, 128,
                                                 ysc, y1, 256, 256);
    r4_stats<<<dim3(256), 256, 0, stream>>>(ysc, stats + 0);
    r4_stats<<<dim3(256), 256, 0, stream>>>(y1, stats + 512);
    r4_bnrelu<<<dim3(256), 256, 0, stream>>>(y1, stats + 512, g1, b1, g1, b1, g1, b1, g1, b1, 0);

    // branch 0 (1x1) and branch 1 (3x3) into obuf cols [0:64) and [64:128)
    r4_gemm<<<dim3(64, 1, 16), 256, 0, stream>>>(y1, 256, wb0_b, wb0_b, 0, 64,
                                                 obuf, obuf, 1 << 28, 256);
    r4_conv3<<<dim3(64, 16), 256, 0, stream>>>(y1, wb1p, obuf);

    // branch 2 (LGA on s2 = y1 cols 128..191) -> obuf cols [128:192)
    r4_gemm<<<dim3(64, 3, 16), 256, 0, stream>>>(y1 + 128, 256, wq2_b, wq2_b, 0, 64,
                                                 qkv, qkv, 1 << 28, 192);
    r5_kmax<<<dim3(32, 16), 256, 0, stream>>>(qkv, mo2);
    r5_ksum<<<dim3(32, 16), 256, 0, stream>>>(qkv, mo2, lo2);
    r4_softapply<<<dim3(64, 16), 256, 0, stream>>>(qkv, mo2, lo2, sk, vcn);
    r4_zero<<<dim3(256), 256, 0, stream>>>(ctx);
    r4_ctx<<<dim3(8, 16), 256, 0, stream>>>(sk, vcn, ctx);
    r4_mproj<<<dim3(16), 64, 0, stream>>>(Wproj2, ctx, M);
    r4_gemm<<<dim3(64, 1, 16), 256, 0, stream>>>(qkv, 192, M, M, 4096, 64,
                                                 obuf + 128, obuf + 128, 1 << 28, 256);

    // branch 3 (LGA on s3 = y1 cols 192..255) -> obuf cols [192:256)
    r4_gemm<<<dim3(64, 3, 16), 256, 0, stream>>>(y1 + 192, 256, wq3_b, wq3_b, 0, 64,
                                                 qkv, qkv, 1 << 28, 192);
    r5_kmax<<<dim3(32, 16), 256, 0, stream>>>(qkv, mo3);
    r5_ksum<<<dim3(32, 16), 256, 0, stream>>>(qkv, mo3, lo3);
    r4_softapply<<<dim3(64, 16), 256, 0, stream>>>(qkv, mo3, lo3, sk, vcn);
    r4_zero<<<dim3(256), 256, 0, stream>>>(ctx);
    r4_ctx<<<dim3(8, 16), 256, 0, stream>>>(sk, vcn, ctx);
    r4_mproj<<<dim3(16), 64, 0, stream>>>(Wproj3, ctx, M);
    r4_gemm<<<dim3(64, 1, 16), 256, 0, stream>>>(qkv, 192, M, M, 4096, 64,
                                                 obuf + 192, obuf + 192, 1 << 28, 256);

    // concat BN + ReLU (per-quarter params), then conv2
    r4_stats<<<dim3(256), 256, 0, stream>>>(obuf, stats + 1024);
    r4_bnrelu<<<dim3(256), 256, 0, stream>>>(obuf, stats + 1024,
                                             gb0, bb0, gb1, bb1, ga2, ba2, ga3, ba3, 1);
    r4_gemm<<<dim3(64, 4, 16), 256, 0, stream>>>(obuf, 256, w2_b, w2_b, 0, 256,
                                                 y2, y2, 1 << 28, 256);
    r4_stats<<<dim3(256), 256, 0, stream>>>(y2, stats + 1536);
    r4_final<<<dim3(64, 4, 16), 256, 0, stream>>>(y2, ysc, stats + 1536, stats + 0,
                                                  g2, b2, gsc, bsc, (float*)d_out);
}

// Round 6
// 678.297 us; speedup vs baseline: 1.6988x; 1.0177x over previous
//
#include <hip/hip_runtime.h>
#include <hip/hip_bf16.h>

using bf16 = __hip_bfloat16;
typedef __bf16 bf16v8 __attribute__((ext_vector_type(8)));
typedef float f32x4 __attribute__((ext_vector_type(4)));

#define HW 4096      // 64*64 spatial per image
#define ROWS 65536   // 16*HW

// ordered-int mapping for float atomicMax
__device__ __forceinline__ int f2oi(float f) { int i = __float_as_int(f); return i >= 0 ? i : i ^ 0x7FFFFFFF; }
__device__ __forceinline__ float oi2f(int i) { return __int_as_float(i >= 0 ? i : i ^ 0x7FFFFFFF); }

// ---------------- zero helper ------------------------------------------------
__global__ void r4_zero(float* __restrict__ p) {
    p[blockIdx.x * 256 + threadIdx.x] = 0.f;
}

// ------- init: BN sums (2048 f) = 0; softmax m/l slots for both branches -----
__global__ void r5_init(float* __restrict__ stats, int* __restrict__ mo2, float* __restrict__ lo2,
                        int* __restrict__ mo3, float* __restrict__ lo3) {
    int i = blockIdx.x * 256 + threadIdx.x;   // 8 blocks * 256 = 2048
    stats[i] = 0.f;
    if (i < 1024) {
        int neg = f2oi(-1e30f);
        mo2[i] = neg; lo2[i] = 0.f;
        mo3[i] = neg; lo3[i] = 0.f;
    }
}

// ------- convert+transpose x: fp32 [b][c=128][n] -> bf16 [b][n][c=128] -------
__global__ void r4_cvt_x(const float* __restrict__ x, bf16* __restrict__ xT) {
    __shared__ bf16 tile[64 * 65];
    int b = blockIdx.z, c0 = blockIdx.y * 64, n0 = blockIdx.x * 64;
    int t = threadIdx.x;
    for (int i = 0; i < 16; i++) {
        int idx = i * 256 + t;
        int cc = idx >> 6, nn = idx & 63;
        tile[nn * 65 + cc] = __float2bfloat16(x[((size_t)(b * 128 + c0 + cc)) * HW + n0 + nn]);
    }
    __syncthreads();
    for (int i = 0; i < 16; i++) {
        int idx = i * 256 + t;
        int nn = idx >> 6, cc = idx & 63;
        xT[((size_t)(b * HW + n0 + nn)) * 128 + c0 + cc] = tile[nn * 65 + cc];
    }
}

// ------- convert the 6 plain weight matrices fp32 -> bf16 (one launch) -------
__global__ void r4_cvt_w(const float* __restrict__ Wsc, const float* __restrict__ W1,
                         const float* __restrict__ Wb0,
                         const float* __restrict__ Wqkv2, const float* __restrict__ Wqkv3,
                         const float* __restrict__ W2, bf16* __restrict__ wbase) {
    int i = blockIdx.x * 256 + threadIdx.x;   // 624 blocks * 256 = 159744 exact
    const float* s; int off;
    if      (i < 32768)  { s = Wsc;   off = i; }
    else if (i < 65536)  { s = W1;    off = i - 32768; }
    else if (i < 69632)  { s = Wb0;   off = i - 65536; }
    else if (i < 81920)  { s = Wqkv2; off = i - 69632; }
    else if (i < 94208)  { s = Wqkv3; off = i - 81920; }
    else                 { s = W2;    off = i - 94208; }
    wbase[i] = __float2bfloat16(s[off]);
}

// ------- pack+convert Wb1 fp32 [o][c][3][3] -> bf16 [tap][o][c] --------------
__global__ void r4_pack3(const float* __restrict__ w, bf16* __restrict__ wp) {
    int i = blockIdx.x * 256 + threadIdx.x;   // 144*256 = 36864 exact
    int tap = i / 4096, rem = i % 4096;
    int o = rem >> 6, c = rem & 63;
    wp[i] = __float2bfloat16(w[(size_t)(o * 64 + c) * 9 + tap]);
}

// ------- bn params: sc/sh per channel from sums (+optional 4-way quarter) ----
__global__ void r6_bnparam(const float* __restrict__ sums,
                           const float* __restrict__ g0, const float* __restrict__ b0,
                           const float* __restrict__ g1, const float* __restrict__ b1,
                           const float* __restrict__ g2, const float* __restrict__ b2,
                           const float* __restrict__ g3, const float* __restrict__ b3,
                           int quarter, float* __restrict__ sc, float* __restrict__ sh) {
    int ch = threadIdx.x;
    const float *gp, *bp; int ci;
    if (quarter) {
        int qi = ch >> 6; ci = ch & 63;
        gp = qi == 0 ? g0 : qi == 1 ? g1 : qi == 2 ? g2 : g3;
        bp = qi == 0 ? b0 : qi == 1 ? b1 : qi == 2 ? b2 : b3;
    } else { gp = g0; bp = b0; ci = ch; }
    float mean = sums[ch] * (1.f / 65536.f);
    float var  = sums[256 + ch] * (1.f / 65536.f) - mean * mean;
    float s = gp[ci] * rsqrtf(var + 1e-5f);
    sc[ch] = s;
    sh[ch] = bp[ci] - mean * s;
}

// ===== generic GEMM: out[row][o] = sum_k T(A[row][k]) * W[o][k] ==============
// T = optional per-channel bn+relu (asc/ash). Epilogue: LDS tile -> 16B stores
// + optional per-channel sum/sumsq atomics (stats of raw output).
template <int OT>
__global__ __launch_bounds__(256) void r6_gemm(
        const bf16* __restrict__ A, int a_stride,
        const float* __restrict__ asc, const float* __restrict__ ash,
        const bf16* __restrict__ Bw, const bf16* __restrict__ Bw2,
        int b_batch_stride, int K,
        bf16* __restrict__ out0, bf16* __restrict__ out1,
        int split, int out_stride,
        float* __restrict__ stat0, float* __restrict__ stat1,
        int scol0, int scol1) {
    constexpr int NC = OT * 16;          // cols per block
    constexpr int TS = NC + 8;           // tile stride (16B aligned: (NC+8)*2)
    __shared__ float ascS[256], ashS[256];
    __shared__ bf16 tile[64 * TS];
    __shared__ float sredS[4][NC], sredQ[4][NC];

    int wave = threadIdx.x >> 6, lane = threadIdx.x & 63;
    int b = blockIdx.z;
    int lo = lane & 15, quad = lane >> 4;
    long grow = (long)b * HW + blockIdx.x * 64;
    int o_base = blockIdx.y * NC;

    bool has_t = (asc != nullptr);
    if (has_t) {
        for (int i = threadIdx.x; i < K; i += 256) { ascS[i] = asc[i]; ashS[i] = ash[i]; }
        __syncthreads();
    }

    const bf16* arow = A + (grow + wave * 16 + lo) * (long)a_stride + quad * 8;
    const bf16* wrow[OT];
#pragma unroll
    for (int ot = 0; ot < OT; ot++) {
        int o = o_base + ot * 16 + lo;
        const bf16* wb = (o < split) ? (Bw + (long)o * K) : (Bw2 + (long)(o - split) * K);
        wrow[ot] = wb + (long)b * b_batch_stride + quad * 8;
    }

    f32x4 acc[OT];
#pragma unroll
    for (int ot = 0; ot < OT; ot++) acc[ot] = (f32x4){0.f, 0.f, 0.f, 0.f};

    for (int ks = 0; ks < K; ks += 32) {
        bf16v8 av = *(const bf16v8*)(arow + ks);
        if (has_t) {
            int kb = ks + quad * 8;
#pragma unroll
            for (int j = 0; j < 8; j++) {
                float f = (float)av[j] * ascS[kb + j] + ashS[kb + j];
                av[j] = (__bf16)fmaxf(f, 0.f);
            }
        }
#pragma unroll
        for (int ot = 0; ot < OT; ot++) {
            bf16v8 bv = *(const bf16v8*)(wrow[ot] + ks);
            acc[ot] = __builtin_amdgcn_mfma_f32_16x16x32_bf16(av, bv, acc[ot], 0, 0, 0);
        }
    }

    // stage output tile in LDS (local row = wave*16+quad*4+r, local col = ot*16+lo)
#pragma unroll
    for (int ot = 0; ot < OT; ot++) {
#pragma unroll
        for (int r = 0; r < 4; r++)
            tile[(wave * 16 + quad * 4 + r) * TS + ot * 16 + lo] = __float2bfloat16(acc[ot][r]);
    }
    __syncthreads();

    // vectorized 16B stores
    for (int u = threadIdx.x; u < 64 * OT * 2; u += 256) {
        int lr = u / (OT * 2), cg = u % (OT * 2);
        bf16v8 v = *(const bf16v8*)&tile[lr * TS + cg * 8];
        int oc = o_base + cg * 8;
        bf16* op; int c;
        if (oc < split) { op = out0; c = oc; } else { op = out1; c = oc - split; }
        *(bf16v8*)&op[(grow + lr) * (long)out_stride + c] = v;
    }

    // fused BN statistics (sum / sumsq over the 64 rows of this block)
    if (stat0) {
        for (int cl = lane; cl < NC; cl += 64) {
            float s = 0.f, q = 0.f;
#pragma unroll
            for (int i = 0; i < 16; i++) {
                float v = __bfloat162float(tile[(wave * 16 + i) * TS + cl]);
                s += v; q += v * v;
            }
            sredS[wave][cl] = s; sredQ[wave][cl] = q;
        }
        __syncthreads();
        if (threadIdx.x < NC) {
            int t = threadIdx.x;
            float s = sredS[0][t] + sredS[1][t] + sredS[2][t] + sredS[3][t];
            float q = sredQ[0][t] + sredQ[1][t] + sredQ[2][t] + sredQ[3][t];
            int o = o_base + t;
            float* st; int ci;
            if (o < split) { st = stat0; ci = scol0 + o; }
            else           { st = stat1; ci = scol1 + o - split; }
            atomicAdd(&st[ci], s);
            atomicAdd(&st[256 + ci], q);
        }
    }
}

// ---- 3x3 conv on h channels 64..127, with fused bn+relu input transform -----
__global__ __launch_bounds__(256) void r6_conv3(
        const bf16* __restrict__ hT, const bf16* __restrict__ wp,
        const float* __restrict__ asc, const float* __restrict__ ash,
        bf16* __restrict__ obuf, float* __restrict__ stat) {
    __shared__ float ascS[64], ashS[64];
    __shared__ bf16 tile[64 * 72];
    __shared__ float sredS[4][64], sredQ[4][64];
    int wave = threadIdx.x >> 6, lane = threadIdx.x & 63;
    int b = blockIdx.y;
    int n_base = blockIdx.x * 64 + wave * 16;
    int y = n_base >> 6, x0 = n_base & 63;
    int lo = lane & 15, quad = lane >> 4;
    int x = x0 + lo;
    if (threadIdx.x < 64) { ascS[threadIdx.x] = asc[threadIdx.x]; ashS[threadIdx.x] = ash[threadIdx.x]; }
    __syncthreads();

    f32x4 acc[4];
#pragma unroll
    for (int ot = 0; ot < 4; ot++) acc[ot] = (f32x4){0.f, 0.f, 0.f, 0.f};

    for (int dy = -1; dy <= 1; dy++) {
        int yy = y + dy;
        bool rv = (yy >= 0) && (yy < 64);
        for (int dx = -1; dx <= 1; dx++) {
            int xx = x + dx;
            bool valid = rv && (xx >= 0) && (xx < 64);
            int tap = (dy + 1) * 3 + (dx + 1);
            const bf16* wt = wp + tap * 4096 + quad * 8;
            long srow = (long)b * HW + yy * 64 + xx;
#pragma unroll
            for (int ks = 0; ks < 64; ks += 32) {
                bf16v8 av = (bf16v8){0, 0, 0, 0, 0, 0, 0, 0};
                if (valid) {
                    av = *(const bf16v8*)(hT + srow * 256 + 64 + ks + quad * 8);
                    int kb = ks + quad * 8;
#pragma unroll
                    for (int j = 0; j < 8; j++) {
                        float f = (float)av[j] * ascS[kb + j] + ashS[kb + j];
                        av[j] = (__bf16)fmaxf(f, 0.f);
                    }
                }
#pragma unroll
                for (int ot = 0; ot < 4; ot++) {
                    bf16v8 bv = *(const bf16v8*)(wt + (ot * 16 + lo) * 64 + ks);
                    acc[ot] = __builtin_amdgcn_mfma_f32_16x16x32_bf16(av, bv, acc[ot], 0, 0, 0);
                }
            }
        }
    }
    long grow = (long)b * HW + blockIdx.x * 64;
#pragma unroll
    for (int ot = 0; ot < 4; ot++) {
#pragma unroll
        for (int r = 0; r < 4; r++)
            tile[(wave * 16 + quad * 4 + r) * 72 + ot * 16 + lo] = __float2bfloat16(acc[ot][r]);
    }
    __syncthreads();
    for (int u = threadIdx.x; u < 512; u += 256) {
        int lr = u >> 3, cg = u & 7;
        bf16v8 v = *(const bf16v8*)&tile[lr * 72 + cg * 8];
        *(bf16v8*)&obuf[(grow + lr) * 256 + 64 + cg * 8] = v;
    }
    {
        float s = 0.f, q = 0.f;
#pragma unroll
        for (int i = 0; i < 16; i++) {
            float v = __bfloat162float(tile[(wave * 16 + i) * 72 + lane]);
            s += v; q += v * v;
        }
        sredS[wave][lane] = s; sredQ[wave][lane] = q;
        __syncthreads();
        if (threadIdx.x < 64) {
            int t = threadIdx.x;
            float ss = sredS[0][t] + sredS[1][t] + sredS[2][t] + sredS[3][t];
            float qq = sredQ[0][t] + sredQ[1][t] + sredQ[2][t] + sredQ[3][t];
            atomicAdd(&stat[64 + t], ss);
            atomicAdd(&stat[256 + 64 + t], qq);
        }
    }
}

// ------- per-(b,c) max of k-slice, wide grid + ordered-int atomicMax ---------
__global__ void r5_kmax(const bf16* __restrict__ qkvT, int* __restrict__ mo) {
    __shared__ float red[256];
    int b = blockIdx.y, t = threadIdx.x, c = t & 63, sub = t >> 6;   // 4 subs
    long n0 = (long)blockIdx.x * 128 + sub * 32;
    const bf16* base = qkvT + ((long)b * HW + n0) * 192 + 64 + c;
    float mx = -1e30f;
    for (int n = 0; n < 32; n++)
        mx = fmaxf(mx, __bfloat162float(base[n * 192]));
    red[t] = mx; __syncthreads();
    if (t < 64) {
        float m = fmaxf(fmaxf(red[t], red[t + 64]), fmaxf(red[t + 128], red[t + 192]));
        atomicMax(&mo[b * 64 + t], f2oi(m));
    }
}

// ------- per-(b,c) sum of exp(k - m), wide grid + atomicAdd ------------------
__global__ void r5_ksum(const bf16* __restrict__ qkvT, const int* __restrict__ mo,
                        float* __restrict__ lo_) {
    __shared__ float red[256];
    int b = blockIdx.y, t = threadIdx.x, c = t & 63, sub = t >> 6;
    long n0 = (long)blockIdx.x * 128 + sub * 32;
    float m = oi2f(mo[b * 64 + c]);
    const bf16* base = qkvT + ((long)b * HW + n0) * 192 + 64 + c;
    float s = 0.f;
    for (int n = 0; n < 32; n++)
        s += expf(__bfloat162float(base[n * 192]) - m);
    red[t] = s; __syncthreads();
    if (t < 64) {
        float tot = red[t] + red[t + 64] + red[t + 128] + red[t + 192];
        atomicAdd(&lo_[b * 64 + t], tot);
    }
}

// ------- apply softmax to k, transpose k,v to [b][c][n] (vector reads) -------
__global__ void r6_softapply(const bf16* __restrict__ qkvT,
                             const int* __restrict__ m_in, const float* __restrict__ l_in,
                             bf16* __restrict__ softk, bf16* __restrict__ vcn) {
    __shared__ bf16 lk[64 * 65];
    __shared__ bf16 lv[64 * 65];
    __shared__ float mS[64], ilS[64];
    int b = blockIdx.y, n0 = blockIdx.x * 64;
    int t = threadIdx.x;
    if (t < 64) { mS[t] = oi2f(m_in[b * 64 + t]); ilS[t] = 1.f / l_in[b * 64 + t]; }
    __syncthreads();
    for (int half = 0; half < 2; half++) {
        int r = half * 32 + (t >> 3), cg = t & 7;
        const bf16* row = qkvT + ((long)b * HW + n0 + r) * 192;
        bf16v8 k8 = *(const bf16v8*)(row + 64 + cg * 8);
        bf16v8 v8 = *(const bf16v8*)(row + 128 + cg * 8);
#pragma unroll
        for (int j = 0; j < 8; j++) {
            int c = cg * 8 + j;
            lk[c * 65 + r] = __float2bfloat16(expf((float)k8[j] - mS[c]) * ilS[c]);
            lv[c * 65 + r] = (bf16)v8[j];
        }
    }
    __syncthreads();
    for (int i = 0; i < 16; i++) {
        int idx = i * 256 + t; int c = idx >> 6, r = idx & 63;
        long o = ((long)b * 64 + c) * HW + n0 + r;
        softk[o] = lk[c * 65 + r];
        vcn[o]   = lv[c * 65 + r];
    }
}

// ---------------- ctx[b][c][d] = sum_n softk[c][n] * v[d][n] -----------------
__global__ __launch_bounds__(256) void r4_ctx(
        const bf16* __restrict__ softk, const bf16* __restrict__ vcn,
        float* __restrict__ ctx) {
    int wave = threadIdx.x >> 6, lane = threadIdx.x & 63;
    int b = blockIdx.y;
    int n0 = blockIdx.x * 512;
    int lo = lane & 15, quad = lane >> 4;
    const bf16* arow  = softk + ((long)b * 64 + wave * 16 + lo) * HW + n0 + quad * 8;
    const bf16* bbase = vcn + (long)b * 64 * HW + n0 + quad * 8;
    f32x4 acc[4];
#pragma unroll
    for (int ot = 0; ot < 4; ot++) acc[ot] = (f32x4){0.f, 0.f, 0.f, 0.f};
    for (int ks = 0; ks < 512; ks += 32) {
        bf16v8 av = *(const bf16v8*)(arow + ks);
#pragma unroll
        for (int ot = 0; ot < 4; ot++) {
            bf16v8 bv = *(const bf16v8*)(bbase + (ot * 16 + lo) * HW + ks);
            acc[ot] = __builtin_amdgcn_mfma_f32_16x16x32_bf16(av, bv, acc[ot], 0, 0, 0);
        }
    }
#pragma unroll
    for (int ot = 0; ot < 4; ot++) {
#pragma unroll
        for (int r = 0; r < 4; r++) {
            int c = wave * 16 + quad * 4 + r;
            int d = ot * 16 + lo;
            atomicAdd(&ctx[((long)b * 64 + c) * 64 + d], acc[ot][r]);
        }
    }
}

// ------- M[b][e][c] = sum_d Wproj[e][d] * ctx[b][c][d]  (conflict-free) ------
__global__ void r6_mproj(const float* __restrict__ Wp, const float* __restrict__ ctx,
                         bf16* __restrict__ M) {
    __shared__ float lwT[64 * 65];   // lwT[d*65+e] = Wp[e][d]
    __shared__ float lc[64];
    int b = blockIdx.x, e = threadIdx.x;  // 64 threads
    for (int j = 0; j < 64; j++) lwT[j * 65 + e] = Wp[e * 64 + j];
    __syncthreads();
    const float* cb = ctx + (long)b * 4096;
    for (int c = 0; c < 64; c++) {
        lc[e] = cb[c * 64 + e];
        __syncthreads();
        float a = 0.f;
#pragma unroll 8
        for (int d = 0; d < 64; d++) a += lwT[d * 65 + e] * lc[d];
        M[(long)b * 4096 + e * 64 + c] = __float2bfloat16(a);
        __syncthreads();
    }
}

// --------- final: relu(bn2(y2) + bnsc(ysc)), write fp32 NCHW -----------------
__global__ void r6_final(const bf16* __restrict__ y2, const bf16* __restrict__ ysc,
                         const float* __restrict__ s2sums, const float* __restrict__ scsums,
                         const float* __restrict__ g2, const float* __restrict__ b2,
                         const float* __restrict__ gsc, const float* __restrict__ bsc,
                         float* __restrict__ out) {
    __shared__ float lo_[64 * 65];
    __shared__ float sc2[64], sh2[64], scc[64], shc[64];
    int b = blockIdx.z, c0 = blockIdx.y * 64, n0 = blockIdx.x * 64;
    int t = threadIdx.x;
    if (t < 64) {
        int ch = c0 + t;
        float m2 = s2sums[ch] * (1.f / 65536.f);
        float v2 = s2sums[256 + ch] * (1.f / 65536.f) - m2 * m2;
        float s = g2[ch] * rsqrtf(v2 + 1e-5f);
        sc2[t] = s; sh2[t] = b2[ch] - m2 * s;
        float mc = scsums[ch] * (1.f / 65536.f);
        float vc = scsums[256 + ch] * (1.f / 65536.f) - mc * mc;
        float s2_ = gsc[ch] * rsqrtf(vc + 1e-5f);
        scc[t] = s2_; shc[t] = bsc[ch] - mc * s2_;
    }
    __syncthreads();
    for (int half = 0; half < 2; half++) {
        int r = half * 32 + (t >> 3), cc = (t & 7) * 8;
        long row = (long)b * HW + n0 + r;
        bf16v8 a8 = *(const bf16v8*)&y2[row * 256 + c0 + cc];
        bf16v8 s8 = *(const bf16v8*)&ysc[row * 256 + c0 + cc];
#pragma unroll
        for (int j = 0; j < 8; j++) {
            int c = cc + j;
            float v = (float)a8[j] * sc2[c] + sh2[c] + (float)s8[j] * scc[c] + shc[c];
            lo_[c * 65 + r] = fmaxf(v, 0.f);
        }
    }
    __syncthreads();
    for (int i = 0; i < 16; i++) {
        int idx = i * 256 + t; int c = idx >> 6, r = idx & 63;
        out[((long)b * 256 + c0 + c) * HW + n0 + r] = lo_[c * 65 + r];
    }
}

extern "C" void kernel_launch(void* const* d_in, const int* in_sizes, int n_in,
                              void* d_out, int out_size, void* d_ws, size_t ws_size,
                              hipStream_t stream) {
    const float* x     = (const float*)d_in[0];
    const float* Wsc   = (const float*)d_in[1];
    const float* gsc   = (const float*)d_in[2];
    const float* bsc   = (const float*)d_in[3];
    const float* W1    = (const float*)d_in[4];
    const float* g1    = (const float*)d_in[5];
    const float* b1    = (const float*)d_in[6];
    const float* Wb0   = (const float*)d_in[7];
    const float* gb0   = (const float*)d_in[8];
    const float* bb0   = (const float*)d_in[9];
    const float* Wb1   = (const float*)d_in[10];
    const float* gb1   = (const float*)d_in[11];
    const float* bb1   = (const float*)d_in[12];
    const float* Wqkv2 = (const float*)d_in[13];
    const float* Wproj2= (const float*)d_in[14];
    const float* ga2   = (const float*)d_in[15];
    const float* ba2   = (const float*)d_in[16];
    const float* Wqkv3 = (const float*)d_in[17];
    const float* Wproj3= (const float*)d_in[18];
    const float* ga3   = (const float*)d_in[19];
    const float* ba3   = (const float*)d_in[20];
    const float* W2    = (const float*)d_in[21];
    const float* g2    = (const float*)d_in[22];
    const float* b2    = (const float*)d_in[23];

    // ---- workspace map ----
    char* ws = (char*)d_ws;
    float* stats = (float*)ws;                 // 2048 f: set0 ysc@0, set1 y1@512, set2 obuf@1024, set3 y2@1536
    int*   mo2   = (int*)(ws + 8192);
    float* lo2   = (float*)(ws + 12288);
    int*   mo3   = (int*)(ws + 16384);
    float* lo3   = (float*)(ws + 20480);
    float* scY1  = (float*)(ws + 24576);       // 256 f
    float* shY1  = (float*)(ws + 25600);
    float* scOb  = (float*)(ws + 26624);
    float* shOb  = (float*)(ws + 27648);
    float* ctx   = (float*)(ws + 28672);       // 262144 B -> 290816
    bf16*  M     = (bf16*)(ws + 290816);       // 131072 B -> 421888
    bf16*  wbase = (bf16*)(ws + 421888);       // 319488 B -> 741376
    bf16*  wsc_b = wbase;
    bf16*  w1_b  = wbase + 32768;
    bf16*  wb0_b = wbase + 65536;
    bf16*  wq2_b = wbase + 69632;
    bf16*  wq3_b = wbase + 81920;
    bf16*  w2_b  = wbase + 94208;
    bf16*  wb1p  = (bf16*)(ws + 741376);       // 73728 B -> 815104
    bf16*  xT    = (bf16*)(ws + 1048576);      // 16 MiB; dead after big gemm
    bf16*  sk    = xT;                         // 8 MiB reuse
    bf16*  vcn   = (bf16*)(ws + 1048576 + 8388608);
    bf16*  ysc   = (bf16*)(ws + 17825792);     // 32 MiB, live to end
    bf16*  y1    = (bf16*)(ws + 51380224);     // 32 MiB
    bf16*  y2    = y1;                         // alias (y1 dead after qkv3 gemm)
    bf16*  obuf  = (bf16*)d_out;               // 32 MiB bf16 scratch in d_out
    bf16*  qkv   = (bf16*)((char*)d_out + 33554432); // 24 MiB

    r5_init<<<dim3(8), 256, 0, stream>>>(stats, mo2, lo2, mo3, lo3);
    r4_cvt_w<<<dim3(624), 256, 0, stream>>>(Wsc, W1, Wb0, Wqkv2, Wqkv3, W2, wbase);
    r4_pack3<<<dim3(144), 256, 0, stream>>>(Wb1, wb1p);
    r4_cvt_x<<<dim3(64, 2, 16), 256, 0, stream>>>(x, xT);

    // conv_sc + conv1 fused (N=512), stats fused (ysc->set0, y1->set1)
    r6_gemm<8><<<dim3(64, 4, 16), 256, 0, stream>>>(
        xT, 128, nullptr, nullptr, wsc_b, w1_b, 0, 128,
        ysc, y1, 256, 256, stats, stats + 512, 0, 0);
    r6_bnparam<<<1, 256, 0, stream>>>(stats + 512, g1, b1, g1, b1, g1, b1, g1, b1, 0, scY1, shY1);

    // branch 0 (1x1, K=64 on h cols 0..63) and branch 1 (3x3) -> obuf
    r6_gemm<4><<<dim3(64, 1, 16), 256, 0, stream>>>(
        y1, 256, scY1, shY1, wb0_b, wb0_b, 0, 64,
        obuf, obuf, 1 << 28, 256, stats + 1024, stats + 1024, 0, 0);
    r6_conv3<<<dim3(64, 16), 256, 0, stream>>>(y1, wb1p, scY1 + 64, shY1 + 64, obuf, stats + 1024);

    // branch 2 (LGA on h cols 128..191) -> obuf cols [128:192)
    r6_gemm<4><<<dim3(64, 3, 16), 256, 0, stream>>>(
        y1 + 128, 256, scY1 + 128, shY1 + 128, wq2_b, wq2_b, 0, 64,
        qkv, qkv, 1 << 28, 192, nullptr, nullptr, 0, 0);
    r5_kmax<<<dim3(32, 16), 256, 0, stream>>>(qkv, mo2);
    r5_ksum<<<dim3(32, 16), 256, 0, stream>>>(qkv, mo2, lo2);
    r6_softapply<<<dim3(64, 16), 256, 0, stream>>>(qkv, mo2, lo2, sk, vcn);
    r4_zero<<<dim3(256), 256, 0, stream>>>(ctx);
    r4_ctx<<<dim3(8, 16), 256, 0, stream>>>(sk, vcn, ctx);
    r6_mproj<<<dim3(16), 64, 0, stream>>>(Wproj2, ctx, M);
    r6_gemm<4><<<dim3(64, 1, 16), 256, 0, stream>>>(
        qkv, 192, nullptr, nullptr, M, M, 4096, 64,
        obuf + 128, obuf + 128, 1 << 28, 256, stats + 1024, stats + 1024, 128, 128);

    // branch 3 (LGA on h cols 192..255) -> obuf cols [192:256)
    r6_gemm<4><<<dim3(64, 3, 16), 256, 0, stream>>>(
        y1 + 192, 256, scY1 + 192, shY1 + 192, wq3_b, wq3_b, 0, 64,
        qkv, qkv, 1 << 28, 192, nullptr, nullptr, 0, 0);
    r5_kmax<<<dim3(32, 16), 256, 0, stream>>>(qkv, mo3);
    r5_ksum<<<dim3(32, 16), 256, 0, stream>>>(qkv, mo3, lo3);
    r6_softapply<<<dim3(64, 16), 256, 0, stream>>>(qkv, mo3, lo3, sk, vcn);
    r4_zero<<<dim3(256), 256, 0, stream>>>(ctx);
    r4_ctx<<<dim3(8, 16), 256, 0, stream>>>(sk, vcn, ctx);
    r6_mproj<<<dim3(16), 64, 0, stream>>>(Wproj3, ctx, M);
    r6_gemm<4><<<dim3(64, 1, 16), 256, 0, stream>>>(
        qkv, 192, nullptr, nullptr, M, M, 4096, 64,
        obuf + 192, obuf + 192, 1 << 28, 256, stats + 1024, stats + 1024, 192, 192);

    // concat BN params, then conv2 with fused input bn+relu and y2 stats
    r6_bnparam<<<1, 256, 0, stream>>>(stats + 1024, gb0, bb0, gb1, bb1, ga2, ba2, ga3, ba3, 1, scOb, shOb);
    r6_gemm<8><<<dim3(64, 2, 16), 256, 0, stream>>>(
        obuf, 256, scOb, shOb, w2_b, w2_b, 0, 256,
        y2, y2, 1 << 28, 256, stats + 1536, stats + 1536, 0, 0);

    r6_final<<<dim3(64, 4, 16), 256, 0, stream>>>(y2, ysc, stats + 1536, stats + 0,
                                                  g2, b2, gsc, bsc, (float*)d_out);
}

// Round 7
// 589.275 us; speedup vs baseline: 1.9555x; 1.1511x over previous
//
#include <hip/hip_runtime.h>
#include <hip/hip_bf16.h>

using bf16 = __hip_bfloat16;
typedef __bf16 bf16v8 __attribute__((ext_vector_type(8)));
typedef float f32x4 __attribute__((ext_vector_type(4)));

#define HW 4096      // 64*64 spatial per image
#define ROWS 65536   // 16*HW

// ordered-int mapping for float atomicMax
__device__ __forceinline__ int f2oi(float f) { int i = __float_as_int(f); return i >= 0 ? i : i ^ 0x7FFFFFFF; }
__device__ __forceinline__ float oi2f(int i) { return __int_as_float(i >= 0 ? i : i ^ 0x7FFFFFFF); }

// ---------------- zero helper ------------------------------------------------
__global__ void r4_zero(float* __restrict__ p) {
    p[blockIdx.x * 256 + threadIdx.x] = 0.f;
}

// ------- init: BN sums (2048 f) = 0; softmax m/l slots for both branches -----
__global__ void r5_init(float* __restrict__ stats, int* __restrict__ mo2, float* __restrict__ lo2,
                        int* __restrict__ mo3, float* __restrict__ lo3) {
    int i = blockIdx.x * 256 + threadIdx.x;   // 8 blocks * 256 = 2048
    stats[i] = 0.f;
    if (i < 1024) {
        int neg = f2oi(-1e30f);
        mo2[i] = neg; lo2[i] = 0.f;
        mo3[i] = neg; lo3[i] = 0.f;
    }
}

// ------- convert+transpose x: fp32 [b][c=128][n] -> bf16 [b][n][c=128] -------
__global__ void r4_cvt_x(const float* __restrict__ x, bf16* __restrict__ xT) {
    __shared__ bf16 tile[64 * 65];
    int b = blockIdx.z, c0 = blockIdx.y * 64, n0 = blockIdx.x * 64;
    int t = threadIdx.x;
    for (int i = 0; i < 16; i++) {
        int idx = i * 256 + t;
        int cc = idx >> 6, nn = idx & 63;
        tile[nn * 65 + cc] = __float2bfloat16(x[((size_t)(b * 128 + c0 + cc)) * HW + n0 + nn]);
    }
    __syncthreads();
    for (int i = 0; i < 16; i++) {
        int idx = i * 256 + t;
        int nn = idx >> 6, cc = idx & 63;
        xT[((size_t)(b * HW + n0 + nn)) * 128 + c0 + cc] = tile[nn * 65 + cc];
    }
}

// ------- convert the 6 plain weight matrices fp32 -> bf16 (one launch) -------
__global__ void r4_cvt_w(const float* __restrict__ Wsc, const float* __restrict__ W1,
                         const float* __restrict__ Wb0,
                         const float* __restrict__ Wqkv2, const float* __restrict__ Wqkv3,
                         const float* __restrict__ W2, bf16* __restrict__ wbase) {
    int i = blockIdx.x * 256 + threadIdx.x;   // 624 blocks * 256 = 159744 exact
    const float* s; int off;
    if      (i < 32768)  { s = Wsc;   off = i; }
    else if (i < 65536)  { s = W1;    off = i - 32768; }
    else if (i < 69632)  { s = Wb0;   off = i - 65536; }
    else if (i < 81920)  { s = Wqkv2; off = i - 69632; }
    else if (i < 94208)  { s = Wqkv3; off = i - 81920; }
    else                 { s = W2;    off = i - 94208; }
    wbase[i] = __float2bfloat16(s[off]);
}

// ------- pack+convert Wb1 fp32 [o][c][3][3] -> bf16 [tap][o][c] --------------
__global__ void r4_pack3(const float* __restrict__ w, bf16* __restrict__ wp) {
    int i = blockIdx.x * 256 + threadIdx.x;   // 144*256 = 36864 exact
    int tap = i / 4096, rem = i % 4096;
    int o = rem >> 6, c = rem & 63;
    wp[i] = __float2bfloat16(w[(size_t)(o * 64 + c) * 9 + tap]);
}

// ------- bn params: sc/sh per channel from sums (+optional 4-way quarter) ----
__global__ void r6_bnparam(const float* __restrict__ sums,
                           const float* __restrict__ g0, const float* __restrict__ b0,
                           const float* __restrict__ g1, const float* __restrict__ b1,
                           const float* __restrict__ g2, const float* __restrict__ b2,
                           const float* __restrict__ g3, const float* __restrict__ b3,
                           int quarter, float* __restrict__ sc, float* __restrict__ sh) {
    int ch = threadIdx.x;
    const float *gp, *bp; int ci;
    if (quarter) {
        int qi = ch >> 6; ci = ch & 63;
        gp = qi == 0 ? g0 : qi == 1 ? g1 : qi == 2 ? g2 : g3;
        bp = qi == 0 ? b0 : qi == 1 ? b1 : qi == 2 ? b2 : b3;
    } else { gp = g0; bp = b0; ci = ch; }
    float mean = sums[ch] * (1.f / 65536.f);
    float var  = sums[256 + ch] * (1.f / 65536.f) - mean * mean;
    float s = gp[ci] * rsqrtf(var + 1e-5f);
    sc[ch] = s;
    sh[ch] = bp[ci] - mean * s;
}

// ===== r7 GEMM: LDS-staged A and W (kills 16-segment global fragmentation) ===
// out[row][o] = sum_k T(A[row][k]) * W[o][k]; 64 rows x 64 cols per block.
// T = optional bn+relu, applied ONCE at staging time.
// Epilogue: LDS retile -> 16B stores + optional fused per-channel sum/sumsq.
template <int KK>
__global__ __launch_bounds__(256) void r7_gemm(
        const bf16* __restrict__ A, int a_stride,
        const float* __restrict__ asc, const float* __restrict__ ash,
        const bf16* __restrict__ Bw, const bf16* __restrict__ Bw2,
        int b_batch_stride,
        bf16* __restrict__ out0, bf16* __restrict__ out1,
        int split, int out_stride,
        float* __restrict__ stat0, float* __restrict__ stat1,
        int scol0, int scol1) {
    constexpr int SA = KK + 8;           // row stride in elems; (KK+8)/2 % 32 == 4 -> conflict-free b128
    constexpr int CH = KK / 8;           // 16B chunks per row
    __shared__ bf16 As[64 * SA];         // also reused as output tile (64 x 72)
    __shared__ bf16 Ws[64 * SA];
    __shared__ float ascS[KK], ashS[KK];
    __shared__ float sredS[4][64], sredQ[4][64];

    int t = threadIdx.x;
    int wave = t >> 6, lane = t & 63;
    int lo = lane & 15, quad = lane >> 4;
    int b = blockIdx.z;
    long grow = (long)b * HW + blockIdx.x * 64;
    int o_base = blockIdx.y * 64;

    bool has_t = (asc != nullptr);
    if (has_t) {
        for (int i = t; i < KK; i += 256) { ascS[i] = asc[i]; ashS[i] = ash[i]; }
        __syncthreads();
    }

    // ---- stage A (transformed) and W into LDS, coalesced global reads ----
#pragma unroll
    for (int i = 0; i < 64 * CH / 256; i++) {
        int u = i * 256 + t;
        int row = u / CH, ck = u % CH;
        bf16v8 av = *(const bf16v8*)(A + (grow + row) * (long)a_stride + ck * 8);
        if (has_t) {
#pragma unroll
            for (int j = 0; j < 8; j++) {
                float f = (float)av[j] * ascS[ck * 8 + j] + ashS[ck * 8 + j];
                av[j] = (__bf16)fmaxf(f, 0.f);
            }
        }
        *(bf16v8*)&As[row * SA + ck * 8] = av;
        int o = o_base + row;
        const bf16* wb = (o < split) ? (Bw + (long)o * KK) : (Bw2 + (long)(o - split) * KK);
        wb += (long)b * b_batch_stride;
        *(bf16v8*)&Ws[row * SA + ck * 8] = *(const bf16v8*)(wb + ck * 8);
    }
    __syncthreads();

    // ---- MFMA main loop: pure LDS reads ----
    f32x4 acc[4];
#pragma unroll
    for (int ot = 0; ot < 4; ot++) acc[ot] = (f32x4){0.f, 0.f, 0.f, 0.f};
    const bf16* arow = &As[(wave * 16 + lo) * SA + quad * 8];
#pragma unroll
    for (int ks = 0; ks < KK; ks += 32) {
        bf16v8 av = *(const bf16v8*)(arow + ks);
#pragma unroll
        for (int ot = 0; ot < 4; ot++) {
            bf16v8 wv = *(const bf16v8*)&Ws[(ot * 16 + lo) * SA + ks + quad * 8];
            acc[ot] = __builtin_amdgcn_mfma_f32_16x16x32_bf16(av, wv, acc[ot], 0, 0, 0);
        }
    }
    __syncthreads();

    // ---- epilogue: retile (reuse As, stride 72), 16B stores, fused stats ----
#pragma unroll
    for (int ot = 0; ot < 4; ot++) {
#pragma unroll
        for (int r = 0; r < 4; r++)
            As[(wave * 16 + quad * 4 + r) * 72 + ot * 16 + lo] = __float2bfloat16(acc[ot][r]);
    }
    __syncthreads();
#pragma unroll
    for (int i = 0; i < 2; i++) {
        int u = i * 256 + t;
        int lr = u >> 3, cg = u & 7;
        bf16v8 v = *(const bf16v8*)&As[lr * 72 + cg * 8];
        int oc = o_base + cg * 8;
        bf16* op; int c;
        if (oc < split) { op = out0; c = oc; } else { op = out1; c = oc - split; }
        *(bf16v8*)&op[(grow + lr) * (long)out_stride + c] = v;
    }
    if (stat0) {
        float s = 0.f, q = 0.f;
#pragma unroll
        for (int i = 0; i < 16; i++) {
            float v = __bfloat162float(As[(wave * 16 + i) * 72 + lane]);
            s += v; q += v * v;
        }
        sredS[wave][lane] = s; sredQ[wave][lane] = q;
        __syncthreads();
        if (t < 64) {
            float ss = sredS[0][t] + sredS[1][t] + sredS[2][t] + sredS[3][t];
            float qq = sredQ[0][t] + sredQ[1][t] + sredQ[2][t] + sredQ[3][t];
            int o = o_base + t;
            float* st; int ci;
            if (o < split) { st = stat0; ci = scol0 + o; }
            else           { st = stat1; ci = scol1 + o - split; }
            atomicAdd(&st[ci], ss);
            atomicAdd(&st[256 + ci], qq);
        }
    }
}

// ---- 3x3 conv on h channels 64..127, with fused bn+relu input transform -----
__global__ __launch_bounds__(256) void r6_conv3(
        const bf16* __restrict__ hT, const bf16* __restrict__ wp,
        const float* __restrict__ asc, const float* __restrict__ ash,
        bf16* __restrict__ obuf, float* __restrict__ stat) {
    __shared__ float ascS[64], ashS[64];
    __shared__ bf16 tile[64 * 72];
    __shared__ float sredS[4][64], sredQ[4][64];
    int wave = threadIdx.x >> 6, lane = threadIdx.x & 63;
    int b = blockIdx.y;
    int n_base = blockIdx.x * 64 + wave * 16;
    int y = n_base >> 6, x0 = n_base & 63;
    int lo = lane & 15, quad = lane >> 4;
    int x = x0 + lo;
    if (threadIdx.x < 64) { ascS[threadIdx.x] = asc[threadIdx.x]; ashS[threadIdx.x] = ash[threadIdx.x]; }
    __syncthreads();

    f32x4 acc[4];
#pragma unroll
    for (int ot = 0; ot < 4; ot++) acc[ot] = (f32x4){0.f, 0.f, 0.f, 0.f};

    for (int dy = -1; dy <= 1; dy++) {
        int yy = y + dy;
        bool rv = (yy >= 0) && (yy < 64);
        for (int dx = -1; dx <= 1; dx++) {
            int xx = x + dx;
            bool valid = rv && (xx >= 0) && (xx < 64);
            int tap = (dy + 1) * 3 + (dx + 1);
            const bf16* wt = wp + tap * 4096 + quad * 8;
            long srow = (long)b * HW + yy * 64 + xx;
#pragma unroll
            for (int ks = 0; ks < 64; ks += 32) {
                bf16v8 av = (bf16v8){0, 0, 0, 0, 0, 0, 0, 0};
                if (valid) {
                    av = *(const bf16v8*)(hT + srow * 256 + 64 + ks + quad * 8);
                    int kb = ks + quad * 8;
#pragma unroll
                    for (int j = 0; j < 8; j++) {
                        float f = (float)av[j] * ascS[kb + j] + ashS[kb + j];
                        av[j] = (__bf16)fmaxf(f, 0.f);
                    }
                }
#pragma unroll
                for (int ot = 0; ot < 4; ot++) {
                    bf16v8 bv = *(const bf16v8*)(wt + (ot * 16 + lo) * 64 + ks);
                    acc[ot] = __builtin_amdgcn_mfma_f32_16x16x32_bf16(av, bv, acc[ot], 0, 0, 0);
                }
            }
        }
    }
    long grow = (long)b * HW + blockIdx.x * 64;
#pragma unroll
    for (int ot = 0; ot < 4; ot++) {
#pragma unroll
        for (int r = 0; r < 4; r++)
            tile[(wave * 16 + quad * 4 + r) * 72 + ot * 16 + lo] = __float2bfloat16(acc[ot][r]);
    }
    __syncthreads();
    for (int u = threadIdx.x; u < 512; u += 256) {
        int lr = u >> 3, cg = u & 7;
        bf16v8 v = *(const bf16v8*)&tile[lr * 72 + cg * 8];
        *(bf16v8*)&obuf[(grow + lr) * 256 + 64 + cg * 8] = v;
    }
    {
        float s = 0.f, q = 0.f;
#pragma unroll
        for (int i = 0; i < 16; i++) {
            float v = __bfloat162float(tile[(wave * 16 + i) * 72 + lane]);
            s += v; q += v * v;
        }
        sredS[wave][lane] = s; sredQ[wave][lane] = q;
        __syncthreads();
        if (threadIdx.x < 64) {
            int t = threadIdx.x;
            float ss = sredS[0][t] + sredS[1][t] + sredS[2][t] + sredS[3][t];
            float qq = sredQ[0][t] + sredQ[1][t] + sredQ[2][t] + sredQ[3][t];
            atomicAdd(&stat[64 + t], ss);
            atomicAdd(&stat[256 + 64 + t], qq);
        }
    }
}

// ------- per-(b,c) max of k-slice, wide grid + ordered-int atomicMax ---------
__global__ void r5_kmax(const bf16* __restrict__ qkvT, int* __restrict__ mo) {
    __shared__ float red[256];
    int b = blockIdx.y, t = threadIdx.x, c = t & 63, sub = t >> 6;   // 4 subs
    long n0 = (long)blockIdx.x * 128 + sub * 32;
    const bf16* base = qkvT + ((long)b * HW + n0) * 192 + 64 + c;
    float mx = -1e30f;
    for (int n = 0; n < 32; n++)
        mx = fmaxf(mx, __bfloat162float(base[n * 192]));
    red[t] = mx; __syncthreads();
    if (t < 64) {
        float m = fmaxf(fmaxf(red[t], red[t + 64]), fmaxf(red[t + 128], red[t + 192]));
        atomicMax(&mo[b * 64 + t], f2oi(m));
    }
}

// ------- per-(b,c) sum of exp(k - m), wide grid + atomicAdd ------------------
__global__ void r5_ksum(const bf16* __restrict__ qkvT, const int* __restrict__ mo,
                        float* __restrict__ lo_) {
    __shared__ float red[256];
    int b = blockIdx.y, t = threadIdx.x, c = t & 63, sub = t >> 6;
    long n0 = (long)blockIdx.x * 128 + sub * 32;
    float m = oi2f(mo[b * 64 + c]);
    const bf16* base = qkvT + ((long)b * HW + n0) * 192 + 64 + c;
    float s = 0.f;
    for (int n = 0; n < 32; n++)
        s += expf(__bfloat162float(base[n * 192]) - m);
    red[t] = s; __syncthreads();
    if (t < 64) {
        float tot = red[t] + red[t + 64] + red[t + 128] + red[t + 192];
        atomicAdd(&lo_[b * 64 + t], tot);
    }
}

// ------- apply softmax to k, transpose k,v to [b][c][n] (vector reads) -------
__global__ void r6_softapply(const bf16* __restrict__ qkvT,
                             const int* __restrict__ m_in, const float* __restrict__ l_in,
                             bf16* __restrict__ softk, bf16* __restrict__ vcn) {
    __shared__ bf16 lk[64 * 65];
    __shared__ bf16 lv[64 * 65];
    __shared__ float mS[64], ilS[64];
    int b = blockIdx.y, n0 = blockIdx.x * 64;
    int t = threadIdx.x;
    if (t < 64) { mS[t] = oi2f(m_in[b * 64 + t]); ilS[t] = 1.f / l_in[b * 64 + t]; }
    __syncthreads();
    for (int half = 0; half < 2; half++) {
        int r = half * 32 + (t >> 3), cg = t & 7;
        const bf16* row = qkvT + ((long)b * HW + n0 + r) * 192;
        bf16v8 k8 = *(const bf16v8*)(row + 64 + cg * 8);
        bf16v8 v8 = *(const bf16v8*)(row + 128 + cg * 8);
#pragma unroll
        for (int j = 0; j < 8; j++) {
            int c = cg * 8 + j;
            lk[c * 65 + r] = __float2bfloat16(expf((float)k8[j] - mS[c]) * ilS[c]);
            lv[c * 65 + r] = (bf16)v8[j];
        }
    }
    __syncthreads();
    for (int i = 0; i < 16; i++) {
        int idx = i * 256 + t; int c = idx >> 6, r = idx & 63;
        long o = ((long)b * 64 + c) * HW + n0 + r;
        softk[o] = lk[c * 65 + r];
        vcn[o]   = lv[c * 65 + r];
    }
}

// ---------------- ctx[b][c][d] = sum_n softk[c][n] * v[d][n] -----------------
__global__ __launch_bounds__(256) void r4_ctx(
        const bf16* __restrict__ softk, const bf16* __restrict__ vcn,
        float* __restrict__ ctx) {
    int wave = threadIdx.x >> 6, lane = threadIdx.x & 63;
    int b = blockIdx.y;
    int n0 = blockIdx.x * 512;
    int lo = lane & 15, quad = lane >> 4;
    const bf16* arow  = softk + ((long)b * 64 + wave * 16 + lo) * HW + n0 + quad * 8;
    const bf16* bbase = vcn + (long)b * 64 * HW + n0 + quad * 8;
    f32x4 acc[4];
#pragma unroll
    for (int ot = 0; ot < 4; ot++) acc[ot] = (f32x4){0.f, 0.f, 0.f, 0.f};
    for (int ks = 0; ks < 512; ks += 32) {
        bf16v8 av = *(const bf16v8*)(arow + ks);
#pragma unroll
        for (int ot = 0; ot < 4; ot++) {
            bf16v8 bv = *(const bf16v8*)(bbase + (ot * 16 + lo) * HW + ks);
            acc[ot] = __builtin_amdgcn_mfma_f32_16x16x32_bf16(av, bv, acc[ot], 0, 0, 0);
        }
    }
#pragma unroll
    for (int ot = 0; ot < 4; ot++) {
#pragma unroll
        for (int r = 0; r < 4; r++) {
            int c = wave * 16 + quad * 4 + r;
            int d = ot * 16 + lo;
            atomicAdd(&ctx[((long)b * 64 + c) * 64 + d], acc[ot][r]);
        }
    }
}

// ------- M[b][e][c] = sum_d Wproj[e][d] * ctx[b][c][d]  (conflict-free) ------
__global__ void r6_mproj(const float* __restrict__ Wp, const float* __restrict__ ctx,
                         bf16* __restrict__ M) {
    __shared__ float lwT[64 * 65];   // lwT[d*65+e] = Wp[e][d]
    __shared__ float lc[64];
    int b = blockIdx.x, e = threadIdx.x;  // 64 threads
    for (int j = 0; j < 64; j++) lwT[j * 65 + e] = Wp[e * 64 + j];
    __syncthreads();
    const float* cb = ctx + (long)b * 4096;
    for (int c = 0; c < 64; c++) {
        lc[e] = cb[c * 64 + e];
        __syncthreads();
        float a = 0.f;
#pragma unroll 8
        for (int d = 0; d < 64; d++) a += lwT[d * 65 + e] * lc[d];
        M[(long)b * 4096 + e * 64 + c] = __float2bfloat16(a);
        __syncthreads();
    }
}

// --------- final: relu(bn2(y2) + bnsc(ysc)), write fp32 NCHW -----------------
__global__ void r6_final(const bf16* __restrict__ y2, const bf16* __restrict__ ysc,
                         const float* __restrict__ s2sums, const float* __restrict__ scsums,
                         const float* __restrict__ g2, const float* __restrict__ b2,
                         const float* __restrict__ gsc, const float* __restrict__ bsc,
                         float* __restrict__ out) {
    __shared__ float lo_[64 * 65];
    __shared__ float sc2[64], sh2[64], scc[64], shc[64];
    int b = blockIdx.z, c0 = blockIdx.y * 64, n0 = blockIdx.x * 64;
    int t = threadIdx.x;
    if (t < 64) {
        int ch = c0 + t;
        float m2 = s2sums[ch] * (1.f / 65536.f);
        float v2 = s2sums[256 + ch] * (1.f / 65536.f) - m2 * m2;
        float s = g2[ch] * rsqrtf(v2 + 1e-5f);
        sc2[t] = s; sh2[t] = b2[ch] - m2 * s;
        float mc = scsums[ch] * (1.f / 65536.f);
        float vc = scsums[256 + ch] * (1.f / 65536.f) - mc * mc;
        float s2_ = gsc[ch] * rsqrtf(vc + 1e-5f);
        scc[t] = s2_; shc[t] = bsc[ch] - mc * s2_;
    }
    __syncthreads();
    for (int half = 0; half < 2; half++) {
        int r = half * 32 + (t >> 3), cc = (t & 7) * 8;
        long row = (long)b * HW + n0 + r;
        bf16v8 a8 = *(const bf16v8*)&y2[row * 256 + c0 + cc];
        bf16v8 s8 = *(const bf16v8*)&ysc[row * 256 + c0 + cc];
#pragma unroll
        for (int j = 0; j < 8; j++) {
            int c = cc + j;
            float v = (float)a8[j] * sc2[c] + sh2[c] + (float)s8[j] * scc[c] + shc[c];
            lo_[c * 65 + r] = fmaxf(v, 0.f);
        }
    }
    __syncthreads();
    for (int i = 0; i < 16; i++) {
        int idx = i * 256 + t; int c = idx >> 6, r = idx & 63;
        out[((long)b * 256 + c0 + c) * HW + n0 + r] = lo_[c * 65 + r];
    }
}

extern "C" void kernel_launch(void* const* d_in, const int* in_sizes, int n_in,
                              void* d_out, int out_size, void* d_ws, size_t ws_size,
                              hipStream_t stream) {
    const float* x     = (const float*)d_in[0];
    const float* Wsc   = (const float*)d_in[1];
    const float* gsc   = (const float*)d_in[2];
    const float* bsc   = (const float*)d_in[3];
    const float* W1    = (const float*)d_in[4];
    const float* g1    = (const float*)d_in[5];
    const float* b1    = (const float*)d_in[6];
    const float* Wb0   = (const float*)d_in[7];
    const float* gb0   = (const float*)d_in[8];
    const float* bb0   = (const float*)d_in[9];
    const float* Wb1   = (const float*)d_in[10];
    const float* gb1   = (const float*)d_in[11];
    const float* bb1   = (const float*)d_in[12];
    const float* Wqkv2 = (const float*)d_in[13];
    const float* Wproj2= (const float*)d_in[14];
    const float* ga2   = (const float*)d_in[15];
    const float* ba2   = (const float*)d_in[16];
    const float* Wqkv3 = (const float*)d_in[17];
    const float* Wproj3= (const float*)d_in[18];
    const float* ga3   = (const float*)d_in[19];
    const float* ba3   = (const float*)d_in[20];
    const float* W2    = (const float*)d_in[21];
    const float* g2    = (const float*)d_in[22];
    const float* b2    = (const float*)d_in[23];

    // ---- workspace map ----
    char* ws = (char*)d_ws;
    float* stats = (float*)ws;                 // 2048 f: set0 ysc@0, set1 y1@512, set2 obuf@1024, set3 y2@1536
    int*   mo2   = (int*)(ws + 8192);
    float* lo2   = (float*)(ws + 12288);
    int*   mo3   = (int*)(ws + 16384);
    float* lo3   = (float*)(ws + 20480);
    float* scY1  = (float*)(ws + 24576);       // 256 f
    float* shY1  = (float*)(ws + 25600);
    float* scOb  = (float*)(ws + 26624);
    float* shOb  = (float*)(ws + 27648);
    float* ctx   = (float*)(ws + 28672);       // 262144 B -> 290816
    bf16*  M     = (bf16*)(ws + 290816);       // 131072 B -> 421888
    bf16*  wbase = (bf16*)(ws + 421888);       // 319488 B -> 741376
    bf16*  wsc_b = wbase;
    bf16*  w1_b  = wbase + 32768;
    bf16*  wb0_b = wbase + 65536;
    bf16*  wq2_b = wbase + 69632;
    bf16*  wq3_b = wbase + 81920;
    bf16*  w2_b  = wbase + 94208;
    bf16*  wb1p  = (bf16*)(ws + 741376);       // 73728 B -> 815104
    bf16*  xT    = (bf16*)(ws + 1048576);      // 16 MiB; dead after big gemm
    bf16*  sk    = xT;                         // 8 MiB reuse
    bf16*  vcn   = (bf16*)(ws + 1048576 + 8388608);
    bf16*  ysc   = (bf16*)(ws + 17825792);     // 32 MiB, live to end
    bf16*  y1    = (bf16*)(ws + 51380224);     // 32 MiB
    bf16*  y2    = y1;                         // alias (y1 dead after qkv3 gemm)
    bf16*  obuf  = (bf16*)d_out;               // 32 MiB bf16 scratch in d_out
    bf16*  qkv   = (bf16*)((char*)d_out + 33554432); // 24 MiB

    r5_init<<<dim3(8), 256, 0, stream>>>(stats, mo2, lo2, mo3, lo3);
    r4_cvt_w<<<dim3(624), 256, 0, stream>>>(Wsc, W1, Wb0, Wqkv2, Wqkv3, W2, wbase);
    r4_pack3<<<dim3(144), 256, 0, stream>>>(Wb1, wb1p);
    r4_cvt_x<<<dim3(64, 2, 16), 256, 0, stream>>>(x, xT);

    // conv_sc + conv1 fused (O=512), stats fused (ysc->set0, y1->set1)
    r7_gemm<128><<<dim3(64, 8, 16), 256, 0, stream>>>(
        xT, 128, nullptr, nullptr, wsc_b, w1_b, 0,
        ysc, y1, 256, 256, stats, stats + 512, 0, 0);
    r6_bnparam<<<1, 256, 0, stream>>>(stats + 512, g1, b1, g1, b1, g1, b1, g1, b1, 0, scY1, shY1);

    // branch 0 (1x1, K=64 on h cols 0..63) and branch 1 (3x3) -> obuf
    r7_gemm<64><<<dim3(64, 1, 16), 256, 0, stream>>>(
        y1, 256, scY1, shY1, wb0_b, wb0_b, 0,
        obuf, obuf, 1 << 28, 256, stats + 1024, stats + 1024, 0, 0);
    r6_conv3<<<dim3(64, 16), 256, 0, stream>>>(y1, wb1p, scY1 + 64, shY1 + 64, obuf, stats + 1024);

    // branch 2 (LGA on h cols 128..191) -> obuf cols [128:192)
    r7_gemm<64><<<dim3(64, 3, 16), 256, 0, stream>>>(
        y1 + 128, 256, scY1 + 128, shY1 + 128, wq2_b, wq2_b, 0,
        qkv, qkv, 1 << 28, 192, nullptr, nullptr, 0, 0);
    r5_kmax<<<dim3(32, 16), 256, 0, stream>>>(qkv, mo2);
    r5_ksum<<<dim3(32, 16), 256, 0, stream>>>(qkv, mo2, lo2);
    r6_softapply<<<dim3(64, 16), 256, 0, stream>>>(qkv, mo2, lo2, sk, vcn);
    r4_zero<<<dim3(256), 256, 0, stream>>>(ctx);
    r4_ctx<<<dim3(8, 16), 256, 0, stream>>>(sk, vcn, ctx);
    r6_mproj<<<dim3(16), 64, 0, stream>>>(Wproj2, ctx, M);
    r7_gemm<64><<<dim3(64, 1, 16), 256, 0, stream>>>(
        qkv, 192, nullptr, nullptr, M, M, 4096,
        obuf + 128, obuf + 128, 1 << 28, 256, stats + 1024, stats + 1024, 128, 128);

    // branch 3 (LGA on h cols 192..255) -> obuf cols [192:256)
    r7_gemm<64><<<dim3(64, 3, 16), 256, 0, stream>>>(
        y1 + 192, 256, scY1 + 192, shY1 + 192, wq3_b, wq3_b, 0,
        qkv, qkv, 1 << 28, 192, nullptr, nullptr, 0, 0);
    r5_kmax<<<dim3(32, 16), 256, 0, stream>>>(qkv, mo3);
    r5_ksum<<<dim3(32, 16), 256, 0, stream>>>(qkv, mo3, lo3);
    r6_softapply<<<dim3(64, 16), 256, 0, stream>>>(qkv, mo3, lo3, sk, vcn);
    r4_zero<<<dim3(256), 256, 0, stream>>>(ctx);
    r4_ctx<<<dim3(8, 16), 256, 0, stream>>>(sk, vcn, ctx);
    r6_mproj<<<dim3(16), 64, 0, stream>>>(Wproj3, ctx, M);
    r7_gemm<64><<<dim3(64, 1, 16), 256, 0, stream>>>(
        qkv, 192, nullptr, nullptr, M, M, 4096,
        obuf + 192, obuf + 192, 1 << 28, 256, stats + 1024, stats + 1024, 192, 192);

    // concat BN params, then conv2 with fused input bn+relu and y2 stats
    r6_bnparam<<<1, 256, 0, stream>>>(stats + 1024, gb0, bb0, gb1, bb1, ga2, ba2, ga3, ba3, 1, scOb, shOb);
    r7_gemm<256><<<dim3(64, 4, 16), 256, 0, stream>>>(
        obuf, 256, scOb, shOb, w2_b, w2_b, 0,
        y2, y2, 1 << 28, 256, stats + 1536, stats + 1536, 0, 0);

    r6_final<<<dim3(64, 4, 16), 256, 0, stream>>>(y2, ysc, stats + 1536, stats + 0,
                                                  g2, b2, gsc, bsc, (float*)d_out);
}

// Round 8
// 546.814 us; speedup vs baseline: 2.1073x; 1.0777x over previous
//
#include <hip/hip_runtime.h>
#include <hip/hip_bf16.h>

using bf16 = __hip_bfloat16;
typedef __bf16 bf16v8 __attribute__((ext_vector_type(8)));
typedef float f32x4 __attribute__((ext_vector_type(4)));

#define HW 4096      // 64*64 spatial per image
#define ROWS 65536   // 16*HW

// ordered-int mapping for float atomicMax
__device__ __forceinline__ int f2oi(float f) { int i = __float_as_int(f); return i >= 0 ? i : i ^ 0x7FFFFFFF; }
__device__ __forceinline__ float oi2f(int i) { return __int_as_float(i >= 0 ? i : i ^ 0x7FFFFFFF); }

// ---------------- zero helper ------------------------------------------------
__global__ void r4_zero(float* __restrict__ p) {
    p[blockIdx.x * 256 + threadIdx.x] = 0.f;
}

// ------- init: BN sums (2048 f) = 0; softmax m/l slots for both branches -----
__global__ void r5_init(float* __restrict__ stats, int* __restrict__ mo2, float* __restrict__ lo2,
                        int* __restrict__ mo3, float* __restrict__ lo3) {
    int i = blockIdx.x * 256 + threadIdx.x;   // 8 blocks * 256 = 2048
    stats[i] = 0.f;
    if (i < 1024) {
        int neg = f2oi(-1e30f);
        mo2[i] = neg; lo2[i] = 0.f;
        mo3[i] = neg; lo3[i] = 0.f;
    }
}

// ------- convert+transpose x: fp32 [b][c=128][n] -> bf16 [b][n][c=128] -------
__global__ void r4_cvt_x(const float* __restrict__ x, bf16* __restrict__ xT) {
    __shared__ bf16 tile[64 * 65];
    int b = blockIdx.z, c0 = blockIdx.y * 64, n0 = blockIdx.x * 64;
    int t = threadIdx.x;
    for (int i = 0; i < 16; i++) {
        int idx = i * 256 + t;
        int cc = idx >> 6, nn = idx & 63;
        tile[nn * 65 + cc] = __float2bfloat16(x[((size_t)(b * 128 + c0 + cc)) * HW + n0 + nn]);
    }
    __syncthreads();
    for (int i = 0; i < 16; i++) {
        int idx = i * 256 + t;
        int nn = idx >> 6, cc = idx & 63;
        xT[((size_t)(b * HW + n0 + nn)) * 128 + c0 + cc] = tile[nn * 65 + cc];
    }
}

// ------- convert the 6 plain weight matrices fp32 -> bf16 (one launch) -------
__global__ void r4_cvt_w(const float* __restrict__ Wsc, const float* __restrict__ W1,
                         const float* __restrict__ Wb0,
                         const float* __restrict__ Wqkv2, const float* __restrict__ Wqkv3,
                         const float* __restrict__ W2, bf16* __restrict__ wbase) {
    int i = blockIdx.x * 256 + threadIdx.x;   // 624 blocks * 256 = 159744 exact
    const float* s; int off;
    if      (i < 32768)  { s = Wsc;   off = i; }
    else if (i < 65536)  { s = W1;    off = i - 32768; }
    else if (i < 69632)  { s = Wb0;   off = i - 65536; }
    else if (i < 81920)  { s = Wqkv2; off = i - 69632; }
    else if (i < 94208)  { s = Wqkv3; off = i - 81920; }
    else                 { s = W2;    off = i - 94208; }
    wbase[i] = __float2bfloat16(s[off]);
}

// ------- pack+convert Wb1 fp32 [o][c][3][3] -> bf16 [tap][o][c] --------------
__global__ void r4_pack3(const float* __restrict__ w, bf16* __restrict__ wp) {
    int i = blockIdx.x * 256 + threadIdx.x;   // 144*256 = 36864 exact
    int tap = i / 4096, rem = i % 4096;
    int o = rem >> 6, c = rem & 63;
    wp[i] = __float2bfloat16(w[(size_t)(o * 64 + c) * 9 + tap]);
}

// ------- bn params: sc/sh per channel from sums (+optional 4-way quarter) ----
__global__ void r6_bnparam(const float* __restrict__ sums,
                           const float* __restrict__ g0, const float* __restrict__ b0,
                           const float* __restrict__ g1, const float* __restrict__ b1,
                           const float* __restrict__ g2, const float* __restrict__ b2,
                           const float* __restrict__ g3, const float* __restrict__ b3,
                           int quarter, float* __restrict__ sc, float* __restrict__ sh) {
    int ch = threadIdx.x;
    const float *gp, *bp; int ci;
    if (quarter) {
        int qi = ch >> 6; ci = ch & 63;
        gp = qi == 0 ? g0 : qi == 1 ? g1 : qi == 2 ? g2 : g3;
        bp = qi == 0 ? b0 : qi == 1 ? b1 : qi == 2 ? b2 : b3;
    } else { gp = g0; bp = b0; ci = ch; }
    float mean = sums[ch] * (1.f / 65536.f);
    float var  = sums[256 + ch] * (1.f / 65536.f) - mean * mean;
    float s = gp[ci] * rsqrtf(var + 1e-5f);
    sc[ch] = s;
    sh[ch] = bp[ci] - mean * s;
}

// ===== r7 GEMM: LDS-staged A and W ===========================================
template <int KK>
__global__ __launch_bounds__(256) void r7_gemm(
        const bf16* __restrict__ A, int a_stride,
        const float* __restrict__ asc, const float* __restrict__ ash,
        const bf16* __restrict__ Bw, const bf16* __restrict__ Bw2,
        int b_batch_stride,
        bf16* __restrict__ out0, bf16* __restrict__ out1,
        int split, int out_stride,
        float* __restrict__ stat0, float* __restrict__ stat1,
        int scol0, int scol1) {
    constexpr int SA = KK + 8;
    constexpr int CH = KK / 8;
    __shared__ bf16 As[64 * SA];
    __shared__ bf16 Ws[64 * SA];
    __shared__ float ascS[KK], ashS[KK];
    __shared__ float sredS[4][64], sredQ[4][64];

    int t = threadIdx.x;
    int wave = t >> 6, lane = t & 63;
    int lo = lane & 15, quad = lane >> 4;
    int b = blockIdx.z;
    long grow = (long)b * HW + blockIdx.x * 64;
    int o_base = blockIdx.y * 64;

    bool has_t = (asc != nullptr);
    if (has_t) {
        for (int i = t; i < KK; i += 256) { ascS[i] = asc[i]; ashS[i] = ash[i]; }
        __syncthreads();
    }

#pragma unroll
    for (int i = 0; i < 64 * CH / 256; i++) {
        int u = i * 256 + t;
        int row = u / CH, ck = u % CH;
        bf16v8 av = *(const bf16v8*)(A + (grow + row) * (long)a_stride + ck * 8);
        if (has_t) {
#pragma unroll
            for (int j = 0; j < 8; j++) {
                float f = (float)av[j] * ascS[ck * 8 + j] + ashS[ck * 8 + j];
                av[j] = (__bf16)fmaxf(f, 0.f);
            }
        }
        *(bf16v8*)&As[row * SA + ck * 8] = av;
        int o = o_base + row;
        const bf16* wb = (o < split) ? (Bw + (long)o * KK) : (Bw2 + (long)(o - split) * KK);
        wb += (long)b * b_batch_stride;
        *(bf16v8*)&Ws[row * SA + ck * 8] = *(const bf16v8*)(wb + ck * 8);
    }
    __syncthreads();

    f32x4 acc[4];
#pragma unroll
    for (int ot = 0; ot < 4; ot++) acc[ot] = (f32x4){0.f, 0.f, 0.f, 0.f};
    const bf16* arow = &As[(wave * 16 + lo) * SA + quad * 8];
#pragma unroll
    for (int ks = 0; ks < KK; ks += 32) {
        bf16v8 av = *(const bf16v8*)(arow + ks);
#pragma unroll
        for (int ot = 0; ot < 4; ot++) {
            bf16v8 wv = *(const bf16v8*)&Ws[(ot * 16 + lo) * SA + ks + quad * 8];
            acc[ot] = __builtin_amdgcn_mfma_f32_16x16x32_bf16(av, wv, acc[ot], 0, 0, 0);
        }
    }
    __syncthreads();

#pragma unroll
    for (int ot = 0; ot < 4; ot++) {
#pragma unroll
        for (int r = 0; r < 4; r++)
            As[(wave * 16 + quad * 4 + r) * 72 + ot * 16 + lo] = __float2bfloat16(acc[ot][r]);
    }
    __syncthreads();
#pragma unroll
    for (int i = 0; i < 2; i++) {
        int u = i * 256 + t;
        int lr = u >> 3, cg = u & 7;
        bf16v8 v = *(const bf16v8*)&As[lr * 72 + cg * 8];
        int oc = o_base + cg * 8;
        bf16* op; int c;
        if (oc < split) { op = out0; c = oc; } else { op = out1; c = oc - split; }
        *(bf16v8*)&op[(grow + lr) * (long)out_stride + c] = v;
    }
    if (stat0) {
        float s = 0.f, q = 0.f;
#pragma unroll
        for (int i = 0; i < 16; i++) {
            float v = __bfloat162float(As[(wave * 16 + i) * 72 + lane]);
            s += v; q += v * v;
        }
        sredS[wave][lane] = s; sredQ[wave][lane] = q;
        __syncthreads();
        if (t < 64) {
            float ss = sredS[0][t] + sredS[1][t] + sredS[2][t] + sredS[3][t];
            float qq = sredQ[0][t] + sredQ[1][t] + sredQ[2][t] + sredQ[3][t];
            int o = o_base + t;
            float* st; int ci;
            if (o < split) { st = stat0; ci = scol0 + o; }
            else           { st = stat1; ci = scol1 + o - split; }
            atomicAdd(&st[ci], ss);
            atomicAdd(&st[256 + ci], qq);
        }
    }
}

// ===== r8 conv3: full LDS staging (input rows + all 9 tap weights) ===========
// block = 2 y-rows x 64 out channels; grid (32, 16)
__global__ __launch_bounds__(256) void r8_conv3(
        const bf16* __restrict__ hT, const bf16* __restrict__ wp,
        const float* __restrict__ asc, const float* __restrict__ ash,
        bf16* __restrict__ obuf, float* __restrict__ stat) {
    __shared__ bf16 As[4 * 66 * 72];     // rows y-1..y+2, x-halo at 0/65, stride 72
    __shared__ bf16 Wt[9 * 64 * 72];     // [tap][o][k] stride 72
    __shared__ float ascS[64], ashS[64];
    __shared__ float sredS[4][64], sredQ[4][64];

    int t = threadIdx.x;
    int wave = t >> 6, lane = t & 63;
    int lo = lane & 15, quad = lane >> 4;
    int b = blockIdx.y, y0 = blockIdx.x * 2;

    if (t < 64) { ascS[t] = asc[t]; ashS[t] = ash[t]; }
    // weights: 9*64*8 = 4608 v8-chunks
#pragma unroll
    for (int i = 0; i < 18; i++) {
        int u = i * 256 + t;
        int tap = u >> 9, rem = u & 511;
        int o = rem >> 3, ck = rem & 7;
        *(bf16v8*)&Wt[tap * 4608 + o * 72 + ck * 8] =
            *(const bf16v8*)(wp + tap * 4096 + o * 64 + ck * 8);
    }
    __syncthreads();  // ascS ready before transform below
    // input rows: 4 rows x 64 x x 8 chunks = 2048 v8-chunks
#pragma unroll
    for (int i = 0; i < 8; i++) {
        int u = i * 256 + t;
        int row = u >> 9, rem = u & 511;
        int xx = rem >> 3, ck = rem & 7;
        int yy = y0 - 1 + row;
        bf16v8 av = (bf16v8){0, 0, 0, 0, 0, 0, 0, 0};
        if (yy >= 0 && yy < 64) {
            av = *(const bf16v8*)(hT + ((long)b * HW + yy * 64 + xx) * 256 + 64 + ck * 8);
#pragma unroll
            for (int j = 0; j < 8; j++) {
                float f = (float)av[j] * ascS[ck * 8 + j] + ashS[ck * 8 + j];
                av[j] = (__bf16)fmaxf(f, 0.f);
            }
        }
        *(bf16v8*)&As[row * 4752 + (xx + 1) * 72 + ck * 8] = av;
    }
    if (t < 64) {  // x halos = raw zero
        int row = t >> 4, side = (t >> 3) & 1, ck = t & 7;
        *(bf16v8*)&As[row * 4752 + (side ? 65 : 0) * 72 + ck * 8] = (bf16v8){0,0,0,0,0,0,0,0};
    }
    __syncthreads();

    f32x4 acc[2][4];
#pragma unroll
    for (int s = 0; s < 2; s++)
#pragma unroll
        for (int ot = 0; ot < 4; ot++) acc[s][ot] = (f32x4){0.f, 0.f, 0.f, 0.f};

#pragma unroll
    for (int tap = 0; tap < 9; tap++) {
        int dy = tap / 3 - 1, dx = tap % 3 - 1;
#pragma unroll
        for (int ks = 0; ks < 64; ks += 32) {
            bf16v8 wv[4];
#pragma unroll
            for (int ot = 0; ot < 4; ot++)
                wv[ot] = *(const bf16v8*)&Wt[tap * 4608 + (ot * 16 + lo) * 72 + ks + quad * 8];
#pragma unroll
            for (int s = 0; s < 2; s++) {
                int pb = wave * 32 + s * 16;
                int yl = pb >> 6, xb = pb & 63;
                bf16v8 av = *(const bf16v8*)&As[(yl + dy + 1) * 4752 + (xb + lo + dx + 1) * 72 + ks + quad * 8];
#pragma unroll
                for (int ot = 0; ot < 4; ot++)
                    acc[s][ot] = __builtin_amdgcn_mfma_f32_16x16x32_bf16(av, wv[ot], acc[s][ot], 0, 0, 0);
            }
        }
    }
    __syncthreads();  // before reusing As as output tile (128 rows x stride 72)

#pragma unroll
    for (int s = 0; s < 2; s++)
#pragma unroll
        for (int ot = 0; ot < 4; ot++)
#pragma unroll
            for (int r = 0; r < 4; r++)
                As[(wave * 32 + s * 16 + quad * 4 + r) * 72 + ot * 16 + lo] =
                    __float2bfloat16(acc[s][ot][r]);
    __syncthreads();

    long grow = (long)b * HW + y0 * 64;
#pragma unroll
    for (int i = 0; i < 4; i++) {
        int u = i * 256 + t;
        int lr = u >> 3, cg = u & 7;
        bf16v8 v = *(const bf16v8*)&As[lr * 72 + cg * 8];
        *(bf16v8*)&obuf[(grow + lr) * 256 + 64 + cg * 8] = v;
    }
    {
        float s = 0.f, q = 0.f;
#pragma unroll
        for (int i = 0; i < 32; i++) {
            float v = __bfloat162float(As[(wave * 32 + i) * 72 + lane]);
            s += v; q += v * v;
        }
        sredS[wave][lane] = s; sredQ[wave][lane] = q;
        __syncthreads();
        if (t < 64) {
            float ss = sredS[0][t] + sredS[1][t] + sredS[2][t] + sredS[3][t];
            float qq = sredQ[0][t] + sredQ[1][t] + sredQ[2][t] + sredQ[3][t];
            atomicAdd(&stat[64 + t], ss);
            atomicAdd(&stat[256 + 64 + t], qq);
        }
    }
}

// ------- per-(b,c) max of k-slice, wide grid + ordered-int atomicMax ---------
__global__ void r5_kmax(const bf16* __restrict__ qkvT, int* __restrict__ mo) {
    __shared__ float red[256];
    int b = blockIdx.y, t = threadIdx.x, c = t & 63, sub = t >> 6;   // 4 subs
    long n0 = (long)blockIdx.x * 128 + sub * 32;
    const bf16* base = qkvT + ((long)b * HW + n0) * 192 + 64 + c;
    float mx = -1e30f;
    for (int n = 0; n < 32; n++)
        mx = fmaxf(mx, __bfloat162float(base[n * 192]));
    red[t] = mx; __syncthreads();
    if (t < 64) {
        float m = fmaxf(fmaxf(red[t], red[t + 64]), fmaxf(red[t + 128], red[t + 192]));
        atomicMax(&mo[b * 64 + t], f2oi(m));
    }
}

// ------- per-(b,c) sum of exp(k - m), wide grid + atomicAdd ------------------
__global__ void r5_ksum(const bf16* __restrict__ qkvT, const int* __restrict__ mo,
                        float* __restrict__ lo_) {
    __shared__ float red[256];
    int b = blockIdx.y, t = threadIdx.x, c = t & 63, sub = t >> 6;
    long n0 = (long)blockIdx.x * 128 + sub * 32;
    float m = oi2f(mo[b * 64 + c]);
    const bf16* base = qkvT + ((long)b * HW + n0) * 192 + 64 + c;
    float s = 0.f;
    for (int n = 0; n < 32; n++)
        s += expf(__bfloat162float(base[n * 192]) - m);
    red[t] = s; __syncthreads();
    if (t < 64) {
        float tot = red[t] + red[t + 64] + red[t + 128] + red[t + 192];
        atomicAdd(&lo_[b * 64 + t], tot);
    }
}

// ------- apply softmax to k, transpose k,v to [b][c][n] (vector reads) -------
__global__ void r6_softapply(const bf16* __restrict__ qkvT,
                             const int* __restrict__ m_in, const float* __restrict__ l_in,
                             bf16* __restrict__ softk, bf16* __restrict__ vcn) {
    __shared__ bf16 lk[64 * 65];
    __shared__ bf16 lv[64 * 65];
    __shared__ float mS[64], ilS[64];
    int b = blockIdx.y, n0 = blockIdx.x * 64;
    int t = threadIdx.x;
    if (t < 64) { mS[t] = oi2f(m_in[b * 64 + t]); ilS[t] = 1.f / l_in[b * 64 + t]; }
    __syncthreads();
    for (int half = 0; half < 2; half++) {
        int r = half * 32 + (t >> 3), cg = t & 7;
        const bf16* row = qkvT + ((long)b * HW + n0 + r) * 192;
        bf16v8 k8 = *(const bf16v8*)(row + 64 + cg * 8);
        bf16v8 v8 = *(const bf16v8*)(row + 128 + cg * 8);
#pragma unroll
        for (int j = 0; j < 8; j++) {
            int c = cg * 8 + j;
            lk[c * 65 + r] = __float2bfloat16(expf((float)k8[j] - mS[c]) * ilS[c]);
            lv[c * 65 + r] = (bf16)v8[j];
        }
    }
    __syncthreads();
    for (int i = 0; i < 16; i++) {
        int idx = i * 256 + t; int c = idx >> 6, r = idx & 63;
        long o = ((long)b * 64 + c) * HW + n0 + r;
        softk[o] = lk[c * 65 + r];
        vcn[o]   = lv[c * 65 + r];
    }
}

// ===== r8 ctx: LDS-staged; ctx[b][c][d] = sum_n sk[c][n] v[d][n] =============
// grid (32, 16): n-chunks of 128
__global__ __launch_bounds__(256) void r8_ctx(
        const bf16* __restrict__ softk, const bf16* __restrict__ vcn,
        float* __restrict__ ctx) {
    __shared__ bf16 Ks[64 * 136];
    __shared__ bf16 Vs[64 * 136];
    int t = threadIdx.x;
    int wave = t >> 6, lane = t & 63;
    int lo = lane & 15, quad = lane >> 4;
    int b = blockIdx.y;
    long n0 = (long)blockIdx.x * 128;
#pragma unroll
    for (int i = 0; i < 4; i++) {
        int u = i * 256 + t;
        int c = u >> 4, ck = u & 15;
        *(bf16v8*)&Ks[c * 136 + ck * 8] = *(const bf16v8*)(softk + ((long)b * 64 + c) * HW + n0 + ck * 8);
        *(bf16v8*)&Vs[c * 136 + ck * 8] = *(const bf16v8*)(vcn + ((long)b * 64 + c) * HW + n0 + ck * 8);
    }
    __syncthreads();

    f32x4 acc[4];
#pragma unroll
    for (int ot = 0; ot < 4; ot++) acc[ot] = (f32x4){0.f, 0.f, 0.f, 0.f};
#pragma unroll
    for (int ks = 0; ks < 128; ks += 32) {
        bf16v8 av = *(const bf16v8*)&Ks[(wave * 16 + lo) * 136 + ks + quad * 8];
#pragma unroll
        for (int ot = 0; ot < 4; ot++) {
            bf16v8 bv = *(const bf16v8*)&Vs[(ot * 16 + lo) * 136 + ks + quad * 8];
            acc[ot] = __builtin_amdgcn_mfma_f32_16x16x32_bf16(av, bv, acc[ot], 0, 0, 0);
        }
    }
#pragma unroll
    for (int ot = 0; ot < 4; ot++) {
#pragma unroll
        for (int r = 0; r < 4; r++) {
            int c = wave * 16 + quad * 4 + r;
            int d = ot * 16 + lo;
            atomicAdd(&ctx[((long)b * 64 + c) * 64 + d], acc[ot][r]);
        }
    }
}

// ------- M[b][e][c] = sum_d Wproj[e][d] * ctx[b][c][d]  (conflict-free) ------
__global__ void r6_mproj(const float* __restrict__ Wp, const float* __restrict__ ctx,
                         bf16* __restrict__ M) {
    __shared__ float lwT[64 * 65];   // lwT[d*65+e] = Wp[e][d]
    __shared__ float lc[64];
    int b = blockIdx.x, e = threadIdx.x;  // 64 threads
    for (int j = 0; j < 64; j++) lwT[j * 65 + e] = Wp[e * 64 + j];
    __syncthreads();
    const float* cb = ctx + (long)b * 4096;
    for (int c = 0; c < 64; c++) {
        lc[e] = cb[c * 64 + e];
        __syncthreads();
        float a = 0.f;
#pragma unroll 8
        for (int d = 0; d < 64; d++) a += lwT[d * 65 + e] * lc[d];
        M[(long)b * 4096 + e * 64 + c] = __float2bfloat16(a);
        __syncthreads();
    }
}

// --------- final: relu(bn2(y2) + bnsc(ysc)), write fp32 NCHW -----------------
__global__ void r6_final(const bf16* __restrict__ y2, const bf16* __restrict__ ysc,
                         const float* __restrict__ s2sums, const float* __restrict__ scsums,
                         const float* __restrict__ g2, const float* __restrict__ b2,
                         const float* __restrict__ gsc, const float* __restrict__ bsc,
                         float* __restrict__ out) {
    __shared__ float lo_[64 * 65];
    __shared__ float sc2[64], sh2[64], scc[64], shc[64];
    int b = blockIdx.z, c0 = blockIdx.y * 64, n0 = blockIdx.x * 64;
    int t = threadIdx.x;
    if (t < 64) {
        int ch = c0 + t;
        float m2 = s2sums[ch] * (1.f / 65536.f);
        float v2 = s2sums[256 + ch] * (1.f / 65536.f) - m2 * m2;
        float s = g2[ch] * rsqrtf(v2 + 1e-5f);
        sc2[t] = s; sh2[t] = b2[ch] - m2 * s;
        float mc = scsums[ch] * (1.f / 65536.f);
        float vc = scsums[256 + ch] * (1.f / 65536.f) - mc * mc;
        float s2_ = gsc[ch] * rsqrtf(vc + 1e-5f);
        scc[t] = s2_; shc[t] = bsc[ch] - mc * s2_;
    }
    __syncthreads();
    for (int half = 0; half < 2; half++) {
        int r = half * 32 + (t >> 3), cc = (t & 7) * 8;
        long row = (long)b * HW + n0 + r;
        bf16v8 a8 = *(const bf16v8*)&y2[row * 256 + c0 + cc];
        bf16v8 s8 = *(const bf16v8*)&ysc[row * 256 + c0 + cc];
#pragma unroll
        for (int j = 0; j < 8; j++) {
            int c = cc + j;
            float v = (float)a8[j] * sc2[c] + sh2[c] + (float)s8[j] * scc[c] + shc[c];
            lo_[c * 65 + r] = fmaxf(v, 0.f);
        }
    }
    __syncthreads();
    for (int i = 0; i < 16; i++) {
        int idx = i * 256 + t; int c = idx >> 6, r = idx & 63;
        out[((long)b * 256 + c0 + c) * HW + n0 + r] = lo_[c * 65 + r];
    }
}

extern "C" void kernel_launch(void* const* d_in, const int* in_sizes, int n_in,
                              void* d_out, int out_size, void* d_ws, size_t ws_size,
                              hipStream_t stream) {
    const float* x     = (const float*)d_in[0];
    const float* Wsc   = (const float*)d_in[1];
    const float* gsc   = (const float*)d_in[2];
    const float* bsc   = (const float*)d_in[3];
    const float* W1    = (const float*)d_in[4];
    const float* g1    = (const float*)d_in[5];
    const float* b1    = (const float*)d_in[6];
    const float* Wb0   = (const float*)d_in[7];
    const float* gb0   = (const float*)d_in[8];
    const float* bb0   = (const float*)d_in[9];
    const float* Wb1   = (const float*)d_in[10];
    const float* gb1   = (const float*)d_in[11];
    const float* bb1   = (const float*)d_in[12];
    const float* Wqkv2 = (const float*)d_in[13];
    const float* Wproj2= (const float*)d_in[14];
    const float* ga2   = (const float*)d_in[15];
    const float* ba2   = (const float*)d_in[16];
    const float* Wqkv3 = (const float*)d_in[17];
    const float* Wproj3= (const float*)d_in[18];
    const float* ga3   = (const float*)d_in[19];
    const float* ba3   = (const float*)d_in[20];
    const float* W2    = (const float*)d_in[21];
    const float* g2    = (const float*)d_in[22];
    const float* b2    = (const float*)d_in[23];

    // ---- workspace map ----
    char* ws = (char*)d_ws;
    float* stats = (float*)ws;                 // 2048 f: set0 ysc@0, set1 y1@512, set2 obuf@1024, set3 y2@1536
    int*   mo2   = (int*)(ws + 8192);
    float* lo2   = (float*)(ws + 12288);
    int*   mo3   = (int*)(ws + 16384);
    float* lo3   = (float*)(ws + 20480);
    float* scY1  = (float*)(ws + 24576);       // 256 f
    float* shY1  = (float*)(ws + 25600);
    float* scOb  = (float*)(ws + 26624);
    float* shOb  = (float*)(ws + 27648);
    float* ctx   = (float*)(ws + 28672);       // 262144 B -> 290816
    bf16*  M     = (bf16*)(ws + 290816);       // 131072 B -> 421888
    bf16*  wbase = (bf16*)(ws + 421888);       // 319488 B -> 741376
    bf16*  wsc_b = wbase;
    bf16*  w1_b  = wbase + 32768;
    bf16*  wb0_b = wbase + 65536;
    bf16*  wq2_b = wbase + 69632;
    bf16*  wq3_b = wbase + 81920;
    bf16*  w2_b  = wbase + 94208;
    bf16*  wb1p  = (bf16*)(ws + 741376);       // 73728 B -> 815104
    bf16*  xT    = (bf16*)(ws + 1048576);      // 16 MiB; dead after big gemm
    bf16*  sk    = xT;                         // 8 MiB reuse
    bf16*  vcn   = (bf16*)(ws + 1048576 + 8388608);
    bf16*  ysc   = (bf16*)(ws + 17825792);     // 32 MiB, live to end
    bf16*  y1    = (bf16*)(ws + 51380224);     // 32 MiB
    bf16*  y2    = y1;                         // alias (y1 dead after qkv3 gemm)
    bf16*  obuf  = (bf16*)d_out;               // 32 MiB bf16 scratch in d_out
    bf16*  qkv   = (bf16*)((char*)d_out + 33554432); // 24 MiB

    r5_init<<<dim3(8), 256, 0, stream>>>(stats, mo2, lo2, mo3, lo3);
    r4_cvt_w<<<dim3(624), 256, 0, stream>>>(Wsc, W1, Wb0, Wqkv2, Wqkv3, W2, wbase);
    r4_pack3<<<dim3(144), 256, 0, stream>>>(Wb1, wb1p);
    r4_cvt_x<<<dim3(64, 2, 16), 256, 0, stream>>>(x, xT);

    // conv_sc + conv1 fused (O=512), stats fused (ysc->set0, y1->set1)
    r7_gemm<128><<<dim3(64, 8, 16), 256, 0, stream>>>(
        xT, 128, nullptr, nullptr, wsc_b, w1_b, 0,
        ysc, y1, 256, 256, stats, stats + 512, 0, 0);
    r6_bnparam<<<1, 256, 0, stream>>>(stats + 512, g1, b1, g1, b1, g1, b1, g1, b1, 0, scY1, shY1);

    // branch 0 (1x1, K=64 on h cols 0..63) and branch 1 (3x3) -> obuf
    r7_gemm<64><<<dim3(64, 1, 16), 256, 0, stream>>>(
        y1, 256, scY1, shY1, wb0_b, wb0_b, 0,
        obuf, obuf, 1 << 28, 256, stats + 1024, stats + 1024, 0, 0);
    r8_conv3<<<dim3(32, 16), 256, 0, stream>>>(y1, wb1p, scY1 + 64, shY1 + 64, obuf, stats + 1024);

    // branch 2 (LGA on h cols 128..191) -> obuf cols [128:192)
    r7_gemm<64><<<dim3(64, 3, 16), 256, 0, stream>>>(
        y1 + 128, 256, scY1 + 128, shY1 + 128, wq2_b, wq2_b, 0,
        qkv, qkv, 1 << 28, 192, nullptr, nullptr, 0, 0);
    r5_kmax<<<dim3(32, 16), 256, 0, stream>>>(qkv, mo2);
    r5_ksum<<<dim3(32, 16), 256, 0, stream>>>(qkv, mo2, lo2);
    r6_softapply<<<dim3(64, 16), 256, 0, stream>>>(qkv, mo2, lo2, sk, vcn);
    r4_zero<<<dim3(256), 256, 0, stream>>>(ctx);
    r8_ctx<<<dim3(32, 16), 256, 0, stream>>>(sk, vcn, ctx);
    r6_mproj<<<dim3(16), 64, 0, stream>>>(Wproj2, ctx, M);
    r7_gemm<64><<<dim3(64, 1, 16), 256, 0, stream>>>(
        qkv, 192, nullptr, nullptr, M, M, 4096,
        obuf + 128, obuf + 128, 1 << 28, 256, stats + 1024, stats + 1024, 128, 128);

    // branch 3 (LGA on h cols 192..255) -> obuf cols [192:256)
    r7_gemm<64><<<dim3(64, 3, 16), 256, 0, stream>>>(
        y1 + 192, 256, scY1 + 192, shY1 + 192, wq3_b, wq3_b, 0,
        qkv, qkv, 1 << 28, 192, nullptr, nullptr, 0, 0);
    r5_kmax<<<dim3(32, 16), 256, 0, stream>>>(qkv, mo3);
    r5_ksum<<<dim3(32, 16), 256, 0, stream>>>(qkv, mo3, lo3);
    r6_softapply<<<dim3(64, 16), 256, 0, stream>>>(qkv, mo3, lo3, sk, vcn);
    r4_zero<<<dim3(256), 256, 0, stream>>>(ctx);
    r8_ctx<<<dim3(32, 16), 256, 0, stream>>>(sk, vcn, ctx);
    r6_mproj<<<dim3(16), 64, 0, stream>>>(Wproj3, ctx, M);
    r7_gemm<64><<<dim3(64, 1, 16), 256, 0, stream>>>(
        qkv, 192, nullptr, nullptr, M, M, 4096,
        obuf + 192, obuf + 192, 1 << 28, 256, stats + 1024, stats + 1024, 192, 192);

    // concat BN params, then conv2 with fused input bn+relu and y2 stats
    r6_bnparam<<<1, 256, 0, stream>>>(stats + 1024, gb0, bb0, gb1, bb1, ga2, ba2, ga3, ba3, 1, scOb, shOb);
    r7_gemm<256><<<dim3(64, 4, 16), 256, 0, stream>>>(
        obuf, 256, scOb, shOb, w2_b, w2_b, 0,
        y2, y2, 1 << 28, 256, stats + 1536, stats + 1536, 0, 0);

    r6_final<<<dim3(64, 4, 16), 256, 0, stream>>>(y2, ysc, stats + 1536, stats + 0,
                                                  g2, b2, gsc, bsc, (float*)d_out);
}

// Round 9
// 450.037 us; speedup vs baseline: 2.5605x; 1.2150x over previous
//
#include <hip/hip_runtime.h>
#include <hip/hip_bf16.h>

using bf16 = __hip_bfloat16;
typedef __bf16 bf16v8 __attribute__((ext_vector_type(8)));
typedef float f32x4 __attribute__((ext_vector_type(4)));

#define HW 4096      // 64*64 spatial per image
#define ROWS 65536   // 16*HW

// ordered-int mapping for float atomicMax
__device__ __forceinline__ int f2oi(float f) { int i = __float_as_int(f); return i >= 0 ? i : i ^ 0x7FFFFFFF; }
__device__ __forceinline__ float oi2f(int i) { return __int_as_float(i >= 0 ? i : i ^ 0x7FFFFFFF); }

// ---------------- zero helper ------------------------------------------------
__global__ void r4_zero(float* __restrict__ p) {
    p[blockIdx.x * 256 + threadIdx.x] = 0.f;
}

// ------- init: BN sums (2048 f) = 0; softmax m/l slots for both branches -----
__global__ void r5_init(float* __restrict__ stats, int* __restrict__ mo2, float* __restrict__ lo2,
                        int* __restrict__ mo3, float* __restrict__ lo3) {
    int i = blockIdx.x * 256 + threadIdx.x;   // 8 blocks * 256 = 2048
    stats[i] = 0.f;
    if (i < 1024) {
        int neg = f2oi(-1e30f);
        mo2[i] = neg; lo2[i] = 0.f;
        mo3[i] = neg; lo3[i] = 0.f;
    }
}

// ------- convert+transpose x: fp32 [b][c=128][n] -> bf16 [b][n][c=128] -------
__global__ void r4_cvt_x(const float* __restrict__ x, bf16* __restrict__ xT) {
    __shared__ bf16 tile[64 * 65];
    int b = blockIdx.z, c0 = blockIdx.y * 64, n0 = blockIdx.x * 64;
    int t = threadIdx.x;
    for (int i = 0; i < 16; i++) {
        int idx = i * 256 + t;
        int cc = idx >> 6, nn = idx & 63;
        tile[nn * 65 + cc] = __float2bfloat16(x[((size_t)(b * 128 + c0 + cc)) * HW + n0 + nn]);
    }
    __syncthreads();
    for (int i = 0; i < 16; i++) {
        int idx = i * 256 + t;
        int nn = idx >> 6, cc = idx & 63;
        xT[((size_t)(b * HW + n0 + nn)) * 128 + c0 + cc] = tile[nn * 65 + cc];
    }
}

// ------- convert the 6 plain weight matrices fp32 -> bf16 (one launch) -------
__global__ void r4_cvt_w(const float* __restrict__ Wsc, const float* __restrict__ W1,
                         const float* __restrict__ Wb0,
                         const float* __restrict__ Wqkv2, const float* __restrict__ Wqkv3,
                         const float* __restrict__ W2, bf16* __restrict__ wbase) {
    int i = blockIdx.x * 256 + threadIdx.x;   // 624 blocks * 256 = 159744 exact
    const float* s; int off;
    if      (i < 32768)  { s = Wsc;   off = i; }
    else if (i < 65536)  { s = W1;    off = i - 32768; }
    else if (i < 69632)  { s = Wb0;   off = i - 65536; }
    else if (i < 81920)  { s = Wqkv2; off = i - 69632; }
    else if (i < 94208)  { s = Wqkv3; off = i - 81920; }
    else                 { s = W2;    off = i - 94208; }
    wbase[i] = __float2bfloat16(s[off]);
}

// ------- pack+convert Wb1 fp32 [o][c][3][3] -> bf16 [tap][o][c] --------------
__global__ void r4_pack3(const float* __restrict__ w, bf16* __restrict__ wp) {
    int i = blockIdx.x * 256 + threadIdx.x;   // 144*256 = 36864 exact
    int tap = i / 4096, rem = i % 4096;
    int o = rem >> 6, c = rem & 63;
    wp[i] = __float2bfloat16(w[(size_t)(o * 64 + c) * 9 + tap]);
}

// ------- bn params: sc/sh per channel from sums (+optional 4-way quarter) ----
__global__ void r6_bnparam(const float* __restrict__ sums,
                           const float* __restrict__ g0, const float* __restrict__ b0,
                           const float* __restrict__ g1, const float* __restrict__ b1,
                           const float* __restrict__ g2, const float* __restrict__ b2,
                           const float* __restrict__ g3, const float* __restrict__ b3,
                           int quarter, float* __restrict__ sc, float* __restrict__ sh) {
    int ch = threadIdx.x;
    const float *gp, *bp; int ci;
    if (quarter) {
        int qi = ch >> 6; ci = ch & 63;
        gp = qi == 0 ? g0 : qi == 1 ? g1 : qi == 2 ? g2 : g3;
        bp = qi == 0 ? b0 : qi == 1 ? b1 : qi == 2 ? b2 : b3;
    } else { gp = g0; bp = b0; ci = ch; }
    float mean = sums[ch] * (1.f / 65536.f);
    float var  = sums[256 + ch] * (1.f / 65536.f) - mean * mean;
    float s = gp[ci] * rsqrtf(var + 1e-5f);
    sc[ch] = s;
    sh[ch] = bp[ci] - mean * s;
}

// ===== r7 GEMM: LDS-staged A and W ===========================================
template <int KK>
__global__ __launch_bounds__(256) void r7_gemm(
        const bf16* __restrict__ A, int a_stride,
        const float* __restrict__ asc, const float* __restrict__ ash,
        const bf16* __restrict__ Bw, const bf16* __restrict__ Bw2,
        int b_batch_stride,
        bf16* __restrict__ out0, bf16* __restrict__ out1,
        int split, int out_stride,
        float* __restrict__ stat0, float* __restrict__ stat1,
        int scol0, int scol1) {
    constexpr int SA = KK + 8;
    constexpr int CH = KK / 8;
    __shared__ bf16 As[64 * SA];
    __shared__ bf16 Ws[64 * SA];
    __shared__ float ascS[KK], ashS[KK];
    __shared__ float sredS[4][64], sredQ[4][64];

    int t = threadIdx.x;
    int wave = t >> 6, lane = t & 63;
    int lo = lane & 15, quad = lane >> 4;
    int b = blockIdx.z;
    long grow = (long)b * HW + blockIdx.x * 64;
    int o_base = blockIdx.y * 64;

    bool has_t = (asc != nullptr);
    if (has_t) {
        for (int i = t; i < KK; i += 256) { ascS[i] = asc[i]; ashS[i] = ash[i]; }
        __syncthreads();
    }

#pragma unroll
    for (int i = 0; i < 64 * CH / 256; i++) {
        int u = i * 256 + t;
        int row = u / CH, ck = u % CH;
        bf16v8 av = *(const bf16v8*)(A + (grow + row) * (long)a_stride + ck * 8);
        if (has_t) {
#pragma unroll
            for (int j = 0; j < 8; j++) {
                float f = (float)av[j] * ascS[ck * 8 + j] + ashS[ck * 8 + j];
                av[j] = (__bf16)fmaxf(f, 0.f);
            }
        }
        *(bf16v8*)&As[row * SA + ck * 8] = av;
        int o = o_base + row;
        const bf16* wb = (o < split) ? (Bw + (long)o * KK) : (Bw2 + (long)(o - split) * KK);
        wb += (long)b * b_batch_stride;
        *(bf16v8*)&Ws[row * SA + ck * 8] = *(const bf16v8*)(wb + ck * 8);
    }
    __syncthreads();

    f32x4 acc[4];
#pragma unroll
    for (int ot = 0; ot < 4; ot++) acc[ot] = (f32x4){0.f, 0.f, 0.f, 0.f};
    const bf16* arow = &As[(wave * 16 + lo) * SA + quad * 8];
#pragma unroll
    for (int ks = 0; ks < KK; ks += 32) {
        bf16v8 av = *(const bf16v8*)(arow + ks);
#pragma unroll
        for (int ot = 0; ot < 4; ot++) {
            bf16v8 wv = *(const bf16v8*)&Ws[(ot * 16 + lo) * SA + ks + quad * 8];
            acc[ot] = __builtin_amdgcn_mfma_f32_16x16x32_bf16(av, wv, acc[ot], 0, 0, 0);
        }
    }
    __syncthreads();

#pragma unroll
    for (int ot = 0; ot < 4; ot++) {
#pragma unroll
        for (int r = 0; r < 4; r++)
            As[(wave * 16 + quad * 4 + r) * 72 + ot * 16 + lo] = __float2bfloat16(acc[ot][r]);
    }
    __syncthreads();
#pragma unroll
    for (int i = 0; i < 2; i++) {
        int u = i * 256 + t;
        int lr = u >> 3, cg = u & 7;
        bf16v8 v = *(const bf16v8*)&As[lr * 72 + cg * 8];
        int oc = o_base + cg * 8;
        bf16* op; int c;
        if (oc < split) { op = out0; c = oc; } else { op = out1; c = oc - split; }
        *(bf16v8*)&op[(grow + lr) * (long)out_stride + c] = v;
    }
    if (stat0) {
        float s = 0.f, q = 0.f;
#pragma unroll
        for (int i = 0; i < 16; i++) {
            float v = __bfloat162float(As[(wave * 16 + i) * 72 + lane]);
            s += v; q += v * v;
        }
        sredS[wave][lane] = s; sredQ[wave][lane] = q;
        __syncthreads();
        if (t < 64) {
            float ss = sredS[0][t] + sredS[1][t] + sredS[2][t] + sredS[3][t];
            float qq = sredQ[0][t] + sredQ[1][t] + sredQ[2][t] + sredQ[3][t];
            int o = o_base + t;
            float* st; int ci;
            if (o < split) { st = stat0; ci = scol0 + o; }
            else           { st = stat1; ci = scol1 + o - split; }
            atomicAdd(&st[ci], ss);
            atomicAdd(&st[256 + ci], qq);
        }
    }
}

// ===== r8 conv3: full LDS staging (input rows + all 9 tap weights) ===========
// block = 2 y-rows x 64 out channels; grid (32, 16)
__global__ __launch_bounds__(256) void r8_conv3(
        const bf16* __restrict__ hT, const bf16* __restrict__ wp,
        const float* __restrict__ asc, const float* __restrict__ ash,
        bf16* __restrict__ obuf, float* __restrict__ stat) {
    __shared__ bf16 As[4 * 66 * 72];     // rows y-1..y+2, x-halo at 0/65, stride 72
    __shared__ bf16 Wt[9 * 64 * 72];     // [tap][o][k] stride 72
    __shared__ float ascS[64], ashS[64];
    __shared__ float sredS[4][64], sredQ[4][64];

    int t = threadIdx.x;
    int wave = t >> 6, lane = t & 63;
    int lo = lane & 15, quad = lane >> 4;
    int b = blockIdx.y, y0 = blockIdx.x * 2;

    if (t < 64) { ascS[t] = asc[t]; ashS[t] = ash[t]; }
    // weights: 9*64*8 = 4608 v8-chunks
#pragma unroll
    for (int i = 0; i < 18; i++) {
        int u = i * 256 + t;
        int tap = u >> 9, rem = u & 511;
        int o = rem >> 3, ck = rem & 7;
        *(bf16v8*)&Wt[tap * 4608 + o * 72 + ck * 8] =
            *(const bf16v8*)(wp + tap * 4096 + o * 64 + ck * 8);
    }
    __syncthreads();  // ascS ready before transform below
    // input rows: 4 rows x 64 x x 8 chunks = 2048 v8-chunks
#pragma unroll
    for (int i = 0; i < 8; i++) {
        int u = i * 256 + t;
        int row = u >> 9, rem = u & 511;
        int xx = rem >> 3, ck = rem & 7;
        int yy = y0 - 1 + row;
        bf16v8 av = (bf16v8){0, 0, 0, 0, 0, 0, 0, 0};
        if (yy >= 0 && yy < 64) {
            av = *(const bf16v8*)(hT + ((long)b * HW + yy * 64 + xx) * 256 + 64 + ck * 8);
#pragma unroll
            for (int j = 0; j < 8; j++) {
                float f = (float)av[j] * ascS[ck * 8 + j] + ashS[ck * 8 + j];
                av[j] = (__bf16)fmaxf(f, 0.f);
            }
        }
        *(bf16v8*)&As[row * 4752 + (xx + 1) * 72 + ck * 8] = av;
    }
    if (t < 64) {  // x halos = raw zero
        int row = t >> 4, side = (t >> 3) & 1, ck = t & 7;
        *(bf16v8*)&As[row * 4752 + (side ? 65 : 0) * 72 + ck * 8] = (bf16v8){0,0,0,0,0,0,0,0};
    }
    __syncthreads();

    f32x4 acc[2][4];
#pragma unroll
    for (int s = 0; s < 2; s++)
#pragma unroll
        for (int ot = 0; ot < 4; ot++) acc[s][ot] = (f32x4){0.f, 0.f, 0.f, 0.f};

#pragma unroll
    for (int tap = 0; tap < 9; tap++) {
        int dy = tap / 3 - 1, dx = tap % 3 - 1;
#pragma unroll
        for (int ks = 0; ks < 64; ks += 32) {
            bf16v8 wv[4];
#pragma unroll
            for (int ot = 0; ot < 4; ot++)
                wv[ot] = *(const bf16v8*)&Wt[tap * 4608 + (ot * 16 + lo) * 72 + ks + quad * 8];
#pragma unroll
            for (int s = 0; s < 2; s++) {
                int pb = wave * 32 + s * 16;
                int yl = pb >> 6, xb = pb & 63;
                bf16v8 av = *(const bf16v8*)&As[(yl + dy + 1) * 4752 + (xb + lo + dx + 1) * 72 + ks + quad * 8];
#pragma unroll
                for (int ot = 0; ot < 4; ot++)
                    acc[s][ot] = __builtin_amdgcn_mfma_f32_16x16x32_bf16(av, wv[ot], acc[s][ot], 0, 0, 0);
            }
        }
    }
    __syncthreads();  // before reusing As as output tile (128 rows x stride 72)

#pragma unroll
    for (int s = 0; s < 2; s++)
#pragma unroll
        for (int ot = 0; ot < 4; ot++)
#pragma unroll
            for (int r = 0; r < 4; r++)
                As[(wave * 32 + s * 16 + quad * 4 + r) * 72 + ot * 16 + lo] =
                    __float2bfloat16(acc[s][ot][r]);
    __syncthreads();

    long grow = (long)b * HW + y0 * 64;
#pragma unroll
    for (int i = 0; i < 4; i++) {
        int u = i * 256 + t;
        int lr = u >> 3, cg = u & 7;
        bf16v8 v = *(const bf16v8*)&As[lr * 72 + cg * 8];
        *(bf16v8*)&obuf[(grow + lr) * 256 + 64 + cg * 8] = v;
    }
    {
        float s = 0.f, q = 0.f;
#pragma unroll
        for (int i = 0; i < 32; i++) {
            float v = __bfloat162float(As[(wave * 32 + i) * 72 + lane]);
            s += v; q += v * v;
        }
        sredS[wave][lane] = s; sredQ[wave][lane] = q;
        __syncthreads();
        if (t < 64) {
            float ss = sredS[0][t] + sredS[1][t] + sredS[2][t] + sredS[3][t];
            float qq = sredQ[0][t] + sredQ[1][t] + sredQ[2][t] + sredQ[3][t];
            atomicAdd(&stat[64 + t], ss);
            atomicAdd(&stat[256 + 64 + t], qq);
        }
    }
}

// ------- per-(b,c) max of k-slice, wide grid + ordered-int atomicMax ---------
__global__ void r5_kmax(const bf16* __restrict__ qkvT, int* __restrict__ mo) {
    __shared__ float red[256];
    int b = blockIdx.y, t = threadIdx.x, c = t & 63, sub = t >> 6;   // 4 subs
    long n0 = (long)blockIdx.x * 128 + sub * 32;
    const bf16* base = qkvT + ((long)b * HW + n0) * 192 + 64 + c;
    float mx = -1e30f;
    for (int n = 0; n < 32; n++)
        mx = fmaxf(mx, __bfloat162float(base[n * 192]));
    red[t] = mx; __syncthreads();
    if (t < 64) {
        float m = fmaxf(fmaxf(red[t], red[t + 64]), fmaxf(red[t + 128], red[t + 192]));
        atomicMax(&mo[b * 64 + t], f2oi(m));
    }
}

// ------- per-(b,c) sum of exp(k - m), wide grid + atomicAdd ------------------
__global__ void r5_ksum(const bf16* __restrict__ qkvT, const int* __restrict__ mo,
                        float* __restrict__ lo_) {
    __shared__ float red[256];
    int b = blockIdx.y, t = threadIdx.x, c = t & 63, sub = t >> 6;
    long n0 = (long)blockIdx.x * 128 + sub * 32;
    float m = oi2f(mo[b * 64 + c]);
    const bf16* base = qkvT + ((long)b * HW + n0) * 192 + 64 + c;
    float s = 0.f;
    for (int n = 0; n < 32; n++)
        s += expf(__bfloat162float(base[n * 192]) - m);
    red[t] = s; __syncthreads();
    if (t < 64) {
        float tot = red[t] + red[t + 64] + red[t + 128] + red[t + 192];
        atomicAdd(&lo_[b * 64 + t], tot);
    }
}

// ------- apply softmax to k, transpose k,v to [b][c][n] (vector reads) -------
__global__ void r6_softapply(const bf16* __restrict__ qkvT,
                             const int* __restrict__ m_in, const float* __restrict__ l_in,
                             bf16* __restrict__ softk, bf16* __restrict__ vcn) {
    __shared__ bf16 lk[64 * 65];
    __shared__ bf16 lv[64 * 65];
    __shared__ float mS[64], ilS[64];
    int b = blockIdx.y, n0 = blockIdx.x * 64;
    int t = threadIdx.x;
    if (t < 64) { mS[t] = oi2f(m_in[b * 64 + t]); ilS[t] = 1.f / l_in[b * 64 + t]; }
    __syncthreads();
    for (int half = 0; half < 2; half++) {
        int r = half * 32 + (t >> 3), cg = t & 7;
        const bf16* row = qkvT + ((long)b * HW + n0 + r) * 192;
        bf16v8 k8 = *(const bf16v8*)(row + 64 + cg * 8);
        bf16v8 v8 = *(const bf16v8*)(row + 128 + cg * 8);
#pragma unroll
        for (int j = 0; j < 8; j++) {
            int c = cg * 8 + j;
            lk[c * 65 + r] = __float2bfloat16(expf((float)k8[j] - mS[c]) * ilS[c]);
            lv[c * 65 + r] = (bf16)v8[j];
        }
    }
    __syncthreads();
    for (int i = 0; i < 16; i++) {
        int idx = i * 256 + t; int c = idx >> 6, r = idx & 63;
        long o = ((long)b * 64 + c) * HW + n0 + r;
        softk[o] = lk[c * 65 + r];
        vcn[o]   = lv[c * 65 + r];
    }
}

// ===== r8 ctx: LDS-staged; ctx[b][c][d] = sum_n sk[c][n] v[d][n] =============
// grid (32, 16): n-chunks of 128
__global__ __launch_bounds__(256) void r8_ctx(
        const bf16* __restrict__ softk, const bf16* __restrict__ vcn,
        float* __restrict__ ctx) {
    __shared__ bf16 Ks[64 * 136];
    __shared__ bf16 Vs[64 * 136];
    int t = threadIdx.x;
    int wave = t >> 6, lane = t & 63;
    int lo = lane & 15, quad = lane >> 4;
    int b = blockIdx.y;
    long n0 = (long)blockIdx.x * 128;
#pragma unroll
    for (int i = 0; i < 4; i++) {
        int u = i * 256 + t;
        int c = u >> 4, ck = u & 15;
        *(bf16v8*)&Ks[c * 136 + ck * 8] = *(const bf16v8*)(softk + ((long)b * 64 + c) * HW + n0 + ck * 8);
        *(bf16v8*)&Vs[c * 136 + ck * 8] = *(const bf16v8*)(vcn + ((long)b * 64 + c) * HW + n0 + ck * 8);
    }
    __syncthreads();

    f32x4 acc[4];
#pragma unroll
    for (int ot = 0; ot < 4; ot++) acc[ot] = (f32x4){0.f, 0.f, 0.f, 0.f};
#pragma unroll
    for (int ks = 0; ks < 128; ks += 32) {
        bf16v8 av = *(const bf16v8*)&Ks[(wave * 16 + lo) * 136 + ks + quad * 8];
#pragma unroll
        for (int ot = 0; ot < 4; ot++) {
            bf16v8 bv = *(const bf16v8*)&Vs[(ot * 16 + lo) * 136 + ks + quad * 8];
            acc[ot] = __builtin_amdgcn_mfma_f32_16x16x32_bf16(av, bv, acc[ot], 0, 0, 0);
        }
    }
#pragma unroll
    for (int ot = 0; ot < 4; ot++) {
#pragma unroll
        for (int r = 0; r < 4; r++) {
            int c = wave * 16 + quad * 4 + r;
            int d = ot * 16 + lo;
            atomicAdd(&ctx[((long)b * 64 + c) * 64 + d], acc[ot][r]);
        }
    }
}

// ===== r9 mproj: M[b][e][c] = sum_d Wp[e][d]*ctx[b][c][d], no inner barriers =
// grid (16), 256 threads; Wp row in VGPRs, ctx in LDS (b128 broadcast reads)
__global__ __launch_bounds__(256) void r9_mproj(
        const float* __restrict__ Wp, const float* __restrict__ ctx,
        bf16* __restrict__ M) {
    __shared__ float ctxS[64 * 68];   // [c][d], stride 68 keeps float4 alignment
    int b = blockIdx.x, t = threadIdx.x;
    int e = t & 63, cg = t >> 6;
    // stage ctx[b] (4096 floats) into LDS, coalesced
#pragma unroll
    for (int i = 0; i < 16; i++) {
        int u = i * 256 + t;
        ctxS[(u >> 6) * 68 + (u & 63)] = ctx[(long)b * 4096 + u];
    }
    // own Wproj row in registers (L2-resident after block 0)
    float wreg[64];
#pragma unroll
    for (int i = 0; i < 16; i++) {
        float4 v = *(const float4*)&Wp[e * 64 + i * 4];
        wreg[i * 4 + 0] = v.x; wreg[i * 4 + 1] = v.y;
        wreg[i * 4 + 2] = v.z; wreg[i * 4 + 3] = v.w;
    }
    __syncthreads();
#pragma unroll
    for (int ci = 0; ci < 16; ci++) {
        int c = cg * 16 + ci;
        float a = 0.f;
#pragma unroll
        for (int dg = 0; dg < 16; dg++) {
            float4 cv = *(const float4*)&ctxS[c * 68 + dg * 4];
            a += wreg[dg * 4 + 0] * cv.x + wreg[dg * 4 + 1] * cv.y
               + wreg[dg * 4 + 2] * cv.z + wreg[dg * 4 + 3] * cv.w;
        }
        M[(long)b * 4096 + e * 64 + c] = __float2bfloat16(a);
    }
}

// --------- final: relu(bn2(y2) + bnsc(ysc)), write fp32 NCHW -----------------
__global__ void r6_final(const bf16* __restrict__ y2, const bf16* __restrict__ ysc,
                         const float* __restrict__ s2sums, const float* __restrict__ scsums,
                         const float* __restrict__ g2, const float* __restrict__ b2,
                         const float* __restrict__ gsc, const float* __restrict__ bsc,
                         float* __restrict__ out) {
    __shared__ float lo_[64 * 65];
    __shared__ float sc2[64], sh2[64], scc[64], shc[64];
    int b = blockIdx.z, c0 = blockIdx.y * 64, n0 = blockIdx.x * 64;
    int t = threadIdx.x;
    if (t < 64) {
        int ch = c0 + t;
        float m2 = s2sums[ch] * (1.f / 65536.f);
        float v2 = s2sums[256 + ch] * (1.f / 65536.f) - m2 * m2;
        float s = g2[ch] * rsqrtf(v2 + 1e-5f);
        sc2[t] = s; sh2[t] = b2[ch] - m2 * s;
        float mc = scsums[ch] * (1.f / 65536.f);
        float vc = scsums[256 + ch] * (1.f / 65536.f) - mc * mc;
        float s2_ = gsc[ch] * rsqrtf(vc + 1e-5f);
        scc[t] = s2_; shc[t] = bsc[ch] - mc * s2_;
    }
    __syncthreads();
    for (int half = 0; half < 2; half++) {
        int r = half * 32 + (t >> 3), cc = (t & 7) * 8;
        long row = (long)b * HW + n0 + r;
        bf16v8 a8 = *(const bf16v8*)&y2[row * 256 + c0 + cc];
        bf16v8 s8 = *(const bf16v8*)&ysc[row * 256 + c0 + cc];
#pragma unroll
        for (int j = 0; j < 8; j++) {
            int c = cc + j;
            float v = (float)a8[j] * sc2[c] + sh2[c] + (float)s8[j] * scc[c] + shc[c];
            lo_[c * 65 + r] = fmaxf(v, 0.f);
        }
    }
    __syncthreads();
    for (int i = 0; i < 16; i++) {
        int idx = i * 256 + t; int c = idx >> 6, r = idx & 63;
        out[((long)b * 256 + c0 + c) * HW + n0 + r] = lo_[c * 65 + r];
    }
}

extern "C" void kernel_launch(void* const* d_in, const int* in_sizes, int n_in,
                              void* d_out, int out_size, void* d_ws, size_t ws_size,
                              hipStream_t stream) {
    const float* x     = (const float*)d_in[0];
    const float* Wsc   = (const float*)d_in[1];
    const float* gsc   = (const float*)d_in[2];
    const float* bsc   = (const float*)d_in[3];
    const float* W1    = (const float*)d_in[4];
    const float* g1    = (const float*)d_in[5];
    const float* b1    = (const float*)d_in[6];
    const float* Wb0   = (const float*)d_in[7];
    const float* gb0   = (const float*)d_in[8];
    const float* bb0   = (const float*)d_in[9];
    const float* Wb1   = (const float*)d_in[10];
    const float* gb1   = (const float*)d_in[11];
    const float* bb1   = (const float*)d_in[12];
    const float* Wqkv2 = (const float*)d_in[13];
    const float* Wproj2= (const float*)d_in[14];
    const float* ga2   = (const float*)d_in[15];
    const float* ba2   = (const float*)d_in[16];
    const float* Wqkv3 = (const float*)d_in[17];
    const float* Wproj3= (const float*)d_in[18];
    const float* ga3   = (const float*)d_in[19];
    const float* ba3   = (const float*)d_in[20];
    const float* W2    = (const float*)d_in[21];
    const float* g2    = (const float*)d_in[22];
    const float* b2    = (const float*)d_in[23];

    // ---- workspace map ----
    char* ws = (char*)d_ws;
    float* stats = (float*)ws;                 // 2048 f: set0 ysc@0, set1 y1@512, set2 obuf@1024, set3 y2@1536
    int*   mo2   = (int*)(ws + 8192);
    float* lo2   = (float*)(ws + 12288);
    int*   mo3   = (int*)(ws + 16384);
    float* lo3   = (float*)(ws + 20480);
    float* scY1  = (float*)(ws + 24576);       // 256 f
    float* shY1  = (float*)(ws + 25600);
    float* scOb  = (float*)(ws + 26624);
    float* shOb  = (float*)(ws + 27648);
    float* ctx   = (float*)(ws + 28672);       // 262144 B -> 290816
    bf16*  M     = (bf16*)(ws + 290816);       // 131072 B -> 421888
    bf16*  wbase = (bf16*)(ws + 421888);       // 319488 B -> 741376
    bf16*  wsc_b = wbase;
    bf16*  w1_b  = wbase + 32768;
    bf16*  wb0_b = wbase + 65536;
    bf16*  wq2_b = wbase + 69632;
    bf16*  wq3_b = wbase + 81920;
    bf16*  w2_b  = wbase + 94208;
    bf16*  wb1p  = (bf16*)(ws + 741376);       // 73728 B -> 815104
    bf16*  xT    = (bf16*)(ws + 1048576);      // 16 MiB; dead after big gemm
    bf16*  sk    = xT;                         // 8 MiB reuse
    bf16*  vcn   = (bf16*)(ws + 1048576 + 8388608);
    bf16*  ysc   = (bf16*)(ws + 17825792);     // 32 MiB, live to end
    bf16*  y1    = (bf16*)(ws + 51380224);     // 32 MiB
    bf16*  y2    = y1;                         // alias (y1 dead after qkv3 gemm)
    bf16*  obuf  = (bf16*)d_out;               // 32 MiB bf16 scratch in d_out
    bf16*  qkv   = (bf16*)((char*)d_out + 33554432); // 24 MiB

    r5_init<<<dim3(8), 256, 0, stream>>>(stats, mo2, lo2, mo3, lo3);
    r4_cvt_w<<<dim3(624), 256, 0, stream>>>(Wsc, W1, Wb0, Wqkv2, Wqkv3, W2, wbase);
    r4_pack3<<<dim3(144), 256, 0, stream>>>(Wb1, wb1p);
    r4_cvt_x<<<dim3(64, 2, 16), 256, 0, stream>>>(x, xT);

    // conv_sc + conv1 fused (O=512), stats fused (ysc->set0, y1->set1)
    r7_gemm<128><<<dim3(64, 8, 16), 256, 0, stream>>>(
        xT, 128, nullptr, nullptr, wsc_b, w1_b, 0,
        ysc, y1, 256, 256, stats, stats + 512, 0, 0);
    r6_bnparam<<<1, 256, 0, stream>>>(stats + 512, g1, b1, g1, b1, g1, b1, g1, b1, 0, scY1, shY1);

    // branch 0 (1x1, K=64 on h cols 0..63) and branch 1 (3x3) -> obuf
    r7_gemm<64><<<dim3(64, 1, 16), 256, 0, stream>>>(
        y1, 256, scY1, shY1, wb0_b, wb0_b, 0,
        obuf, obuf, 1 << 28, 256, stats + 1024, stats + 1024, 0, 0);
    r8_conv3<<<dim3(32, 16), 256, 0, stream>>>(y1, wb1p, scY1 + 64, shY1 + 64, obuf, stats + 1024);

    // branch 2 (LGA on h cols 128..191) -> obuf cols [128:192)
    r7_gemm<64><<<dim3(64, 3, 16), 256, 0, stream>>>(
        y1 + 128, 256, scY1 + 128, shY1 + 128, wq2_b, wq2_b, 0,
        qkv, qkv, 1 << 28, 192, nullptr, nullptr, 0, 0);
    r5_kmax<<<dim3(32, 16), 256, 0, stream>>>(qkv, mo2);
    r5_ksum<<<dim3(32, 16), 256, 0, stream>>>(qkv, mo2, lo2);
    r6_softapply<<<dim3(64, 16), 256, 0, stream>>>(qkv, mo2, lo2, sk, vcn);
    r4_zero<<<dim3(256), 256, 0, stream>>>(ctx);
    r8_ctx<<<dim3(32, 16), 256, 0, stream>>>(sk, vcn, ctx);
    r9_mproj<<<dim3(16), 256, 0, stream>>>(Wproj2, ctx, M);
    r7_gemm<64><<<dim3(64, 1, 16), 256, 0, stream>>>(
        qkv, 192, nullptr, nullptr, M, M, 4096,
        obuf + 128, obuf + 128, 1 << 28, 256, stats + 1024, stats + 1024, 128, 128);

    // branch 3 (LGA on h cols 192..255) -> obuf cols [192:256)
    r7_gemm<64><<<dim3(64, 3, 16), 256, 0, stream>>>(
        y1 + 192, 256, scY1 + 192, shY1 + 192, wq3_b, wq3_b, 0,
        qkv, qkv, 1 << 28, 192, nullptr, nullptr, 0, 0);
    r5_kmax<<<dim3(32, 16), 256, 0, stream>>>(qkv, mo3);
    r5_ksum<<<dim3(32, 16), 256, 0, stream>>>(qkv, mo3, lo3);
    r6_softapply<<<dim3(64, 16), 256, 0, stream>>>(qkv, mo3, lo3, sk, vcn);
    r4_zero<<<dim3(256), 256, 0, stream>>>(ctx);
    r8_ctx<<<dim3(32, 16), 256, 0, stream>>>(sk, vcn, ctx);
    r9_mproj<<<dim3(16), 256, 0, stream>>>(Wproj3, ctx, M);
    r7_gemm<64><<<dim3(64, 1, 16), 256, 0, stream>>>(
        qkv, 192, nullptr, nullptr, M, M, 4096,
        obuf + 192, obuf + 192, 1 << 28, 256, stats + 1024, stats + 1024, 192, 192);

    // concat BN params, then conv2 with fused input bn+relu and y2 stats
    r6_bnparam<<<1, 256, 0, stream>>>(stats + 1024, gb0, bb0, gb1, bb1, ga2, ba2, ga3, ba3, 1, scOb, shOb);
    r7_gemm<256><<<dim3(64, 4, 16), 256, 0, stream>>>(
        obuf, 256, scOb, shOb, w2_b, w2_b, 0,
        y2, y2, 1 << 28, 256, stats + 1536, stats + 1536, 0, 0);

    r6_final<<<dim3(64, 4, 16), 256, 0, stream>>>(y2, ysc, stats + 1536, stats + 0,
                                                  g2, b2, gsc, bsc, (float*)d_out);
}